// Round 1
// baseline (3050.110 us; speedup 1.0000x reference)
//
#include <hip/hip_runtime.h>
#include <cstdint>

// Problem constants (from reference): x [8,2048,512] f32, codebook [8192,512] f32
constexpr int DD = 512;    // feature dim
constexpr int KK = 8192;   // codebook size
constexpr int BM = 32;     // rows per block
constexpr int BN = 128;    // codewords per k-tile
constexpr int BK = 32;     // D-chunk staged in LDS
constexpr int NT = 256;    // threads per block

// numpy-style pairwise sum of squares over 128 contiguous floats:
// 8 partial sums (stride-8), combined ((r0+r1)+(r2+r3))+((r4+r5)+(r6+r7)).
// fp contract OFF so square (mul) and accumulate (add) round separately,
// matching numpy's  (a*a) array  then pairwise-sum.
__device__ __forceinline__ float pairwise128_sq(const float* __restrict__ p) {
#pragma clang fp contract(off)
  float r[8];
  {
    float4 a = ((const float4*)p)[0];
    float4 b = ((const float4*)p)[1];
    r[0] = a.x * a.x; r[1] = a.y * a.y; r[2] = a.z * a.z; r[3] = a.w * a.w;
    r[4] = b.x * b.x; r[5] = b.y * b.y; r[6] = b.z * b.z; r[7] = b.w * b.w;
  }
  for (int i = 2; i < 32; i += 2) {
    float4 a = ((const float4*)p)[i];
    float4 b = ((const float4*)p)[i + 1];
    r[0] = r[0] + a.x * a.x; r[1] = r[1] + a.y * a.y;
    r[2] = r[2] + a.z * a.z; r[3] = r[3] + a.w * a.w;
    r[4] = r[4] + b.x * b.x; r[5] = r[5] + b.y * b.y;
    r[6] = r[6] + b.z * b.z; r[7] = r[7] + b.w * b.w;
  }
  return ((r[0] + r[1]) + (r[2] + r[3])) + ((r[4] + r[5]) + (r[6] + r[7]));
}

__global__ __launch_bounds__(NT)
void vq_argmin_kernel(const float* __restrict__ X, const float* __restrict__ CB,
                      float* __restrict__ out) {
  // Transposed LDS tiles, +4 pad keeps float4 (16B) alignment per row and
  // breaks the worst write-bank pattern (4-way instead of 8-way).
  __shared__ float Xs[BK][BM + 4];
  __shared__ float Cs[BK][BN + 4];
  __shared__ float xblk[BM][4];
  __shared__ float cblk[BN][4];
  __shared__ float xsq[BM];
  __shared__ float csq[BN];
  __shared__ int bidx[BM];

  const int t  = threadIdx.x;
  const int tx = t & 31;   // 32 col-groups * 4 cols = BN
  const int ty = t >> 5;   // 8 row-groups  * 4 rows = BM
  const long r0 = (long)blockIdx.x * BM;

  // ---- x_sq per row (numpy pairwise over 4 blocks of 128) ----
  if (t < BM * 4) {
    int row = t >> 2, blk = t & 3;
    xblk[row][blk] = pairwise128_sq(X + (r0 + row) * DD + blk * 128);
  }
  __syncthreads();
  if (t < BM) {
#pragma clang fp contract(off)
    xsq[t] = (xblk[t][0] + xblk[t][1]) + (xblk[t][2] + xblk[t][3]);
  }
  __syncthreads();

  uint64_t bestKey[4];
#pragma unroll
  for (int i = 0; i < 4; ++i) bestKey[i] = ~0ull;

  for (int k0 = 0; k0 < KK; k0 += BN) {
    // ---- c_sq for this k-tile (numpy pairwise) ----
#pragma unroll
    for (int it = 0; it < 2; ++it) {
      int task = t + it * NT;          // 512 tasks = 128 codewords x 4 blocks
      int cw = task >> 2, blk = task & 3;
      cblk[cw][blk] = pairwise128_sq(CB + (long)(k0 + cw) * DD + blk * 128);
    }
    __syncthreads();
    if (t < BN) {
#pragma clang fp contract(off)
      csq[t] = (cblk[t][0] + cblk[t][1]) + (cblk[t][2] + cblk[t][3]);
    }
    // csq reads happen after the first staging barrier below -> ordered.

    float acc[4][4];
#pragma unroll
    for (int i = 0; i < 4; ++i)
#pragma unroll
      for (int j = 0; j < 4; ++j) acc[i][j] = 0.0f;

    for (int dc = 0; dc < DD; dc += BK) {
      // stage X chunk: 32 rows x 32 d = 256 float4, 1 per thread (transposed)
      {
        int row = t >> 3, dg = (t & 7) * 4;
        const float4 v = *(const float4*)(X + (r0 + row) * DD + dc + dg);
        Xs[dg + 0][row] = v.x; Xs[dg + 1][row] = v.y;
        Xs[dg + 2][row] = v.z; Xs[dg + 3][row] = v.w;
      }
      // stage C chunk: 128 rows x 32 d = 1024 float4, 4 per thread (transposed)
#pragma unroll
      for (int it = 0; it < 4; ++it) {
        int idx = t + it * NT;
        int kr = idx >> 3, dg = (idx & 7) * 4;
        const float4 v = *(const float4*)(CB + (long)(k0 + kr) * DD + dc + dg);
        Cs[dg + 0][kr] = v.x; Cs[dg + 1][kr] = v.y;
        Cs[dg + 2][kr] = v.z; Cs[dg + 3][kr] = v.w;
      }
      __syncthreads();
#pragma unroll
      for (int d = 0; d < BK; ++d) {
        const float4 xa = *(const float4*)&Xs[d][ty * 4];
        const float4 cb = *(const float4*)&Cs[d][tx * 4];
        acc[0][0] = __builtin_fmaf(xa.x, cb.x, acc[0][0]);
        acc[0][1] = __builtin_fmaf(xa.x, cb.y, acc[0][1]);
        acc[0][2] = __builtin_fmaf(xa.x, cb.z, acc[0][2]);
        acc[0][3] = __builtin_fmaf(xa.x, cb.w, acc[0][3]);
        acc[1][0] = __builtin_fmaf(xa.y, cb.x, acc[1][0]);
        acc[1][1] = __builtin_fmaf(xa.y, cb.y, acc[1][1]);
        acc[1][2] = __builtin_fmaf(xa.y, cb.z, acc[1][2]);
        acc[1][3] = __builtin_fmaf(xa.y, cb.w, acc[1][3]);
        acc[2][0] = __builtin_fmaf(xa.z, cb.x, acc[2][0]);
        acc[2][1] = __builtin_fmaf(xa.z, cb.y, acc[2][1]);
        acc[2][2] = __builtin_fmaf(xa.z, cb.z, acc[2][2]);
        acc[2][3] = __builtin_fmaf(xa.z, cb.w, acc[2][3]);
        acc[3][0] = __builtin_fmaf(xa.w, cb.x, acc[3][0]);
        acc[3][1] = __builtin_fmaf(xa.w, cb.y, acc[3][1]);
        acc[3][2] = __builtin_fmaf(xa.w, cb.z, acc[3][2]);
        acc[3][3] = __builtin_fmaf(xa.w, cb.w, acc[3][3]);
      }
      __syncthreads();
    }

    // ---- epilogue: dist = (x_sq - 2*dot) + c_sq, fold into running best ----
    {
#pragma clang fp contract(off)
#pragma unroll
      for (int i = 0; i < 4; ++i) {
        float xs = xsq[ty * 4 + i];
#pragma unroll
        for (int j = 0; j < 4; ++j) {
          int kx = k0 + tx * 4 + j;
          float m = 2.0f * acc[i][j];          // exact (power of 2)
          float t1 = xs - m;                   // one rounding (matches np)
          float dist = t1 + csq[tx * 4 + j];   // one rounding (matches np)
          uint32_t u = __float_as_uint(dist);
          u = (u & 0x80000000u) ? ~u : (u | 0x80000000u);  // sortable map
          uint64_t key = ((uint64_t)u << 32) | (uint32_t)kx;
          if (key < bestKey[i]) bestKey[i] = key;          // min dist, then min idx
        }
      }
    }
  }

  // ---- reduce best across the 32 tx lanes (same ty -> same rows) ----
#pragma unroll
  for (int i = 0; i < 4; ++i) {
    unsigned long long k = bestKey[i];
    for (int m = 16; m; m >>= 1) {
      unsigned long long o = __shfl_xor(k, m, 64);
      if (o < k) k = o;
    }
    if (tx == 0) bidx[ty * 4 + i] = (int)(k & 0xFFFFFFFFu);
  }
  __syncthreads();

  // ---- gather winning codewords to out (coalesced float4) ----
#pragma unroll
  for (int it = 0; it < 16; ++it) {
    int idx = t + it * NT;           // 32 rows * 128 float4 = 4096
    int row = idx >> 7;
    int c4 = idx & 127;
    const float4 v = *(const float4*)(CB + (long)bidx[row] * DD + c4 * 4);
    *(float4*)(out + (r0 + row) * DD + c4 * 4) = v;
  }
}

extern "C" void kernel_launch(void* const* d_in, const int* in_sizes, int n_in,
                              void* d_out, int out_size, void* d_ws, size_t ws_size,
                              hipStream_t stream) {
  const float* X  = (const float*)d_in[0];   // [16384, 512]
  const float* CB = (const float*)d_in[1];   // [8192, 512]
  float* out = (float*)d_out;                // [16384, 512]
  const int nrows = in_sizes[0] / DD;        // 16384
  dim3 grid(nrows / BM), block(NT);
  hipLaunchKernelGGL(vq_argmin_kernel, grid, block, 0, stream, X, CB, out);
}

// Round 2
// 2133.938 us; speedup vs baseline: 1.4293x; 1.4293x over previous
//
#include <hip/hip_runtime.h>
#include <cstdint>

// x [8,2048,512] f32 -> 16384 rows; codebook [8192,512] f32
constexpr int DD = 512;    // feature dim
constexpr int KK = 8192;   // codebook size
constexpr int BM = 128;    // rows per block tile
constexpr int BN = 128;    // codewords per k-tile
constexpr int BK = 32;     // D-chunk staged in LDS
constexpr int NT = 256;    // threads per block
constexpr int KSPLIT = 4;  // codebook split across blocks
constexpr int KPB = KK / KSPLIT;  // 2048 codewords per block
constexpr int PAD = 4;

// numpy-style pairwise sum of squares over 128 contiguous floats
// (8 stride-8 partials, combined ((r0+r1)+(r2+r3))+((r4+r5)+(r6+r7))).
__device__ __forceinline__ float pairwise128_sq(const float* __restrict__ p) {
#pragma clang fp contract(off)
  float r[8];
  {
    float4 a = ((const float4*)p)[0];
    float4 b = ((const float4*)p)[1];
    r[0] = a.x * a.x; r[1] = a.y * a.y; r[2] = a.z * a.z; r[3] = a.w * a.w;
    r[4] = b.x * b.x; r[5] = b.y * b.y; r[6] = b.z * b.z; r[7] = b.w * b.w;
  }
  for (int i = 2; i < 32; i += 2) {
    float4 a = ((const float4*)p)[i];
    float4 b = ((const float4*)p)[i + 1];
    r[0] = r[0] + a.x * a.x; r[1] = r[1] + a.y * a.y;
    r[2] = r[2] + a.z * a.z; r[3] = r[3] + a.w * a.w;
    r[4] = r[4] + b.x * b.x; r[5] = r[5] + b.y * b.y;
    r[6] = r[6] + b.z * b.z; r[7] = r[7] + b.w * b.w;
  }
  return ((r[0] + r[1]) + (r[2] + r[3])) + ((r[4] + r[5]) + (r[6] + r[7]));
}

// Kernel 1: per (128-row block, K/4 slice) -> best packed key per row,
// written into the row's own first 32 bytes of `out` (4 x uint64 slots).
__global__ __launch_bounds__(NT)
void vq_partial_kernel(const float* __restrict__ X, const float* __restrict__ CB,
                       float* __restrict__ keyout) {
  __shared__ float Xs[BK][BM + PAD];
  __shared__ float Cs[BK][BN + PAD];
  __shared__ float xblk[BM][4];
  __shared__ float cblk[BN][4];
  __shared__ float xsq[BM];
  __shared__ float csq[BN];

  const int t  = threadIdx.x;
  const int tx = t & 15;   // 16 col-thread groups
  const int ty = t >> 4;   // 16 row-thread groups
  const int bid = blockIdx.x;
  // XCD-aware decomposition: blocks on one XCD share a ksplit (codebook
  // slice = 4MB = one XCD L2). Bijective for grid=512.
  const int xcd = bid & 7;
  const int loc = bid >> 3;                  // 0..63
  const int ksplit = xcd >> 1;               // 0..3
  const int rowblk = (xcd & 1) * 64 + loc;   // 0..127
  const long r0 = (long)rowblk * BM;
  const int kbase = ksplit * KPB;

  // ---- x_sq per row (numpy pairwise: 4 blocks of 128) ----
#pragma unroll
  for (int it = 0; it < 2; ++it) {
    int task = t + it * NT;
    int row = task >> 2, blk = task & 3;
    xblk[row][blk] = pairwise128_sq(X + (r0 + row) * DD + blk * 128);
  }
  __syncthreads();
  if (t < BM) {
#pragma clang fp contract(off)
    xsq[t] = (xblk[t][0] + xblk[t][1]) + (xblk[t][2] + xblk[t][3]);
  }

  uint64_t bestKey[8];
#pragma unroll
  for (int i = 0; i < 8; ++i) bestKey[i] = ~0ull;

  float4 xr[4], cr[4];

  for (int kt = 0; kt < KPB / BN; ++kt) {
    const int k0 = kbase + kt * BN;
    __syncthreads();  // prior tile's compute / csq reads complete

    // preload dc=0 chunk into regs (latency hidden under cblk work)
#pragma unroll
    for (int it = 0; it < 4; ++it) {
      int idx = t + it * NT;
      int row = idx >> 3, dg = (idx & 7) * 4;
      xr[it] = *(const float4*)(X + (r0 + row) * DD + dg);
      cr[it] = *(const float4*)(CB + (long)(k0 + row) * DD + dg);
    }
    // ---- c_sq partials for this tile ----
#pragma unroll
    for (int it = 0; it < 2; ++it) {
      int task = t + it * NT;
      int cw = task >> 2, blk = task & 3;
      cblk[cw][blk] = pairwise128_sq(CB + (long)(k0 + cw) * DD + blk * 128);
    }
    __syncthreads();
    if (t < BN) {
#pragma clang fp contract(off)
      csq[t] = (cblk[t][0] + cblk[t][1]) + (cblk[t][2] + cblk[t][3]);
    }
    // csq ordered before epilogue reads by the dc-loop barriers.

    float acc[8][8];
#pragma unroll
    for (int i = 0; i < 8; ++i)
#pragma unroll
      for (int j = 0; j < 8; ++j) acc[i][j] = 0.0f;

    for (int dc = 0; dc < DD; dc += BK) {
      // regs -> LDS (transposed)
#pragma unroll
      for (int it = 0; it < 4; ++it) {
        int idx = t + it * NT;
        int row = idx >> 3, dg = (idx & 7) * 4;
        Xs[dg + 0][row] = xr[it].x; Xs[dg + 1][row] = xr[it].y;
        Xs[dg + 2][row] = xr[it].z; Xs[dg + 3][row] = xr[it].w;
        Cs[dg + 0][row] = cr[it].x; Cs[dg + 1][row] = cr[it].y;
        Cs[dg + 2][row] = cr[it].z; Cs[dg + 3][row] = cr[it].w;
      }
      // prefetch next chunk (completes under the compute phase)
      if (dc + BK < DD) {
#pragma unroll
        for (int it = 0; it < 4; ++it) {
          int idx = t + it * NT;
          int row = idx >> 3, dg = (idx & 7) * 4 + dc + BK;
          xr[it] = *(const float4*)(X + (r0 + row) * DD + dg);
          cr[it] = *(const float4*)(CB + (long)(k0 + row) * DD + dg);
        }
      }
      __syncthreads();
#pragma unroll 4
      for (int d = 0; d < BK; ++d) {
        const float4 xa0 = *(const float4*)&Xs[d][ty * 4];
        const float4 xa1 = *(const float4*)&Xs[d][64 + ty * 4];
        const float4 cb0 = *(const float4*)&Cs[d][tx * 4];
        const float4 cb1 = *(const float4*)&Cs[d][64 + tx * 4];
        const float xv[8] = {xa0.x, xa0.y, xa0.z, xa0.w,
                             xa1.x, xa1.y, xa1.z, xa1.w};
        const float cv[8] = {cb0.x, cb0.y, cb0.z, cb0.w,
                             cb1.x, cb1.y, cb1.z, cb1.w};
#pragma unroll
        for (int i = 0; i < 8; ++i)
#pragma unroll
          for (int j = 0; j < 8; ++j)
            acc[i][j] = __builtin_fmaf(xv[i], cv[j], acc[i][j]);
      }
      __syncthreads();
    }

    // ---- epilogue: dist = (x_sq - 2*dot) + c_sq, fold into best keys ----
    {
#pragma clang fp contract(off)
#pragma unroll
      for (int i = 0; i < 8; ++i) {
        int rl = (i < 4) ? (ty * 4 + i) : (64 + ty * 4 + (i - 4));
        float xs = xsq[rl];
#pragma unroll
        for (int j = 0; j < 8; ++j) {
          int cl = (j < 4) ? (tx * 4 + j) : (64 + tx * 4 + (j - 4));
          float m = 2.0f * acc[i][j];       // exact
          float t1 = xs - m;                // one rounding
          float dist = t1 + csq[cl];        // one rounding
          uint32_t u = __float_as_uint(dist);
          u = (u & 0x80000000u) ? ~u : (u | 0x80000000u);  // sortable
          uint64_t key = ((uint64_t)u << 32) | (uint32_t)(k0 + cl);
          if (key < bestKey[i]) bestKey[i] = key;
        }
      }
    }
  }

  // ---- reduce across the 16 tx lanes (lane bits 0..3), write key slot ----
#pragma unroll
  for (int i = 0; i < 8; ++i) {
    unsigned long long k = bestKey[i];
#pragma unroll
    for (int m = 1; m <= 8; m <<= 1) {
      unsigned long long o = __shfl_xor(k, m, 64);
      if (o < k) k = o;
    }
    if (tx == 0) {
      int rl = (i < 4) ? (ty * 4 + i) : (64 + ty * 4 + (i - 4));
      *(unsigned long long*)(keyout + (r0 + rl) * DD + ksplit * 2) = k;
    }
  }
}

// Kernel 2: per 32 rows, min-reduce the 4 key slots, gather codeword.
__global__ __launch_bounds__(NT)
void vq_reduce_gather_kernel(const float* __restrict__ CB, float* __restrict__ out) {
  __shared__ int bidx[32];
  const int t = threadIdx.x;
  const long r0 = (long)blockIdx.x * 32;
  if (t < 32) {
    const unsigned long long* kp =
        (const unsigned long long*)(out + (r0 + t) * DD);
    unsigned long long k = kp[0];
#pragma unroll
    for (int s = 1; s < KSPLIT; ++s) {
      unsigned long long o = kp[s];
      if (o < k) k = o;
    }
    bidx[t] = (int)(k & 0xffffffffu);
  }
  __syncthreads();
#pragma unroll
  for (int it = 0; it < 16; ++it) {
    int idx = t + it * NT;
    int row = idx >> 7;
    int c4 = idx & 127;
    const float4 v = *(const float4*)(CB + (long)bidx[row] * DD + c4 * 4);
    *(float4*)(out + (r0 + row) * DD + c4 * 4) = v;
  }
}

extern "C" void kernel_launch(void* const* d_in, const int* in_sizes, int n_in,
                              void* d_out, int out_size, void* d_ws, size_t ws_size,
                              hipStream_t stream) {
  const float* X  = (const float*)d_in[0];   // [16384, 512]
  const float* CB = (const float*)d_in[1];   // [8192, 512]
  float* out = (float*)d_out;                // [16384, 512]
  const int nrows = in_sizes[0] / DD;        // 16384
  dim3 block(NT);
  dim3 grid1((nrows / BM) * KSPLIT);         // 512
  dim3 grid2(nrows / 32);                    // 512
  hipLaunchKernelGGL(vq_partial_kernel, grid1, block, 0, stream, X, CB, out);
  hipLaunchKernelGGL(vq_reduce_gather_kernel, grid2, block, 0, stream, CB, out);
}

// Round 4
// 854.864 us; speedup vs baseline: 3.5679x; 2.4962x over previous
//
#include <hip/hip_runtime.h>
#include <cstdint>

constexpr int DD = 512;       // feature dim
constexpr int KK = 8192;      // codebook size
constexpr int NROWS = 16384;  // x rows
constexpr int GNT = 256;
#define MARGIN 1.0f

constexpr size_t BH_ELEMS = (size_t)KK * 1024;        // ushort (hi|lo halves of CB)
constexpr size_t KEY_ELEMS = (size_t)NROWS * 128;     // ull keys (2 per 128-col block)
constexpr size_t WS_NEEDED = BH_ELEMS * 2 + (size_t)KK * 4 + KEY_ELEMS * 8;  // ~33.6 MB

typedef __attribute__((ext_vector_type(8))) short short8v;
typedef __attribute__((ext_vector_type(4))) float floatx4;
typedef unsigned long long ull;

__device__ __forceinline__ ull umin64(ull a, ull b) { return a < b ? a : b; }
__device__ __forceinline__ uint32_t fsort(float f) {
  uint32_t u = __float_as_uint(f);
  return (u & 0x80000000u) ? ~u : (u | 0x80000000u);
}
__device__ __forceinline__ float funsort(uint32_t u) {
  uint32_t f = (u & 0x80000000u) ? (u ^ 0x80000000u) : ~u;
  return __uint_as_float(f);
}
__device__ __forceinline__ ushort f2bfu(float f) {
  uint32_t u = __float_as_uint(f);
  return (ushort)((u + 0x7fffu + ((u >> 16) & 1u)) >> 16);  // RNE
}

// numpy-style pairwise sum of squares over 128 contiguous floats
__device__ __forceinline__ float pairwise128_sq(const float* __restrict__ p) {
#pragma clang fp contract(off)
  float r[8];
  {
    float4 a = ((const float4*)p)[0];
    float4 b = ((const float4*)p)[1];
    r[0] = a.x * a.x; r[1] = a.y * a.y; r[2] = a.z * a.z; r[3] = a.w * a.w;
    r[4] = b.x * b.x; r[5] = b.y * b.y; r[6] = b.z * b.z; r[7] = b.w * b.w;
  }
  for (int i = 2; i < 32; i += 2) {
    float4 a = ((const float4*)p)[i];
    float4 b = ((const float4*)p)[i + 1];
    r[0] = r[0] + a.x * a.x; r[1] = r[1] + a.y * a.y;
    r[2] = r[2] + a.z * a.z; r[3] = r[3] + a.w * a.w;
    r[4] = r[4] + b.x * b.x; r[5] = r[5] + b.y * b.y;
    r[6] = r[6] + b.z * b.z; r[7] = r[7] + b.w * b.w;
  }
  return ((r[0] + r[1]) + (r[2] + r[3])) + ((r[4] + r[5]) + (r[6] + r[7]));
}

// ---------------- pre-pass: split CB fp32 -> [hi | lo] bf16 halves ----------------
__global__ __launch_bounds__(256)
void split_kernel(const float* __restrict__ src, ushort* __restrict__ dst) {
  int idx = blockIdx.x * 256 + threadIdx.x;  // one float4 per thread
  int row = idx >> 7, c4 = idx & 127;
  float4 v = *(const float4*)(src + (size_t)row * DD + c4 * 4);
  float vv[4] = {v.x, v.y, v.z, v.w};
  uint32_t h[4], l[4];
#pragma unroll
  for (int i = 0; i < 4; ++i) {
    h[i] = (uint32_t)f2bfu(vv[i]);
    float hf = __uint_as_float(h[i] << 16);
    l[i] = (uint32_t)f2bfu(vv[i] - hf);
  }
  ushort* d1 = dst + (size_t)row * 1024 + c4 * 4;
  *(uint2*)d1 = make_uint2(h[0] | (h[1] << 16), h[2] | (h[3] << 16));
  *(uint2*)(d1 + 512) = make_uint2(l[0] | (l[1] << 16), l[2] | (l[3] << 16));
}

// ---------------- pre-pass: c_sq (numpy pairwise) ----------------
__global__ __launch_bounds__(256)
void csq_kernel(const float* __restrict__ CB, float* __restrict__ csq) {
  __shared__ float cblk[64][4];
  int t = threadIdx.x;
  int r0 = blockIdx.x * 64;
  int row = t >> 2, blk = t & 3;
  cblk[row][blk] = pairwise128_sq(CB + (size_t)(r0 + row) * DD + blk * 128);
  __syncthreads();
  if (t < 64) {
#pragma clang fp contract(off)
    csq[r0 + t] = (cblk[t][0] + cblk[t][1]) + (cblk[t][2] + cblk[t][3]);
  }
}

// ---------------- screening GEMM: keys -> d_ws (d_out untouched) ----------------
__global__ __launch_bounds__(GNT, 2)
void vq_screen_kernel(const float* __restrict__ X, const ushort* __restrict__ Bsp,
                      const float* __restrict__ csq, ull* __restrict__ keys) {
  __shared__ ushort AhS[128 * 64];
  __shared__ ushort AlS[128 * 64];
  __shared__ ushort BhS[128 * 64];
  __shared__ ushort BlS[128 * 64];
  __shared__ ull mb[128][2][2];

  const int t = threadIdx.x;
  const int L = t & 63;
  const int w = t >> 6;
  const int wr = (w >> 1) * 64, wc = (w & 1) * 64;

  // XCD-aware swizzle, bijective for 8192 blocks
  const int bid = blockIdx.x;
  const int swz = (bid & 7) * 1024 + (bid >> 3);
  const int rb = swz & 127, cb = swz >> 7;
  const size_t r0 = (size_t)rb * 128, c0 = (size_t)cb * 128;

  // staging task mapping: 4 tasks/thread; row_c = trow + 32c, k-group kg (8 elems)
  const int kg = t & 7;
  const int trow = t >> 3;  // 0..31
  const int swzoff = (kg * 8) ^ ((trow & 7) * 8);  // (trow+32c)&7 == trow&7

  floatx4 acc[4][4];
#pragma unroll
  for (int m = 0; m < 4; ++m)
#pragma unroll
    for (int n = 0; n < 4; ++n) acc[m][n] = (floatx4){0.f, 0.f, 0.f, 0.f};

  float4 ax[8];
  short8v bhv[4], blv[4];

#define LOADCHUNK(DC)                                                            \
  {                                                                              \
    _Pragma("unroll") for (int c = 0; c < 4; ++c) {                              \
      const int row = trow + 32 * c;                                             \
      const float* pa = X + (r0 + row) * DD + (DC) + kg * 8;                     \
      ax[2 * c] = ((const float4*)pa)[0];                                        \
      ax[2 * c + 1] = ((const float4*)pa)[1];                                    \
      const ushort* pb = Bsp + (c0 + row) * 1024 + (DC) + kg * 8;                \
      bhv[c] = *(const short8v*)pb;                                              \
      blv[c] = *(const short8v*)(pb + 512);                                      \
    }                                                                            \
  }

  LOADCHUNK(0);

  for (int ch = 0; ch < 8; ++ch) {
    // ---- write phase: cvt A to hi/lo bf16, store A+B to swizzled LDS ----
#pragma unroll
    for (int c = 0; c < 4; ++c) {
      const int off = (trow + 32 * c) * 64 + swzoff;
      float vv[8] = {ax[2 * c].x, ax[2 * c].y, ax[2 * c].z, ax[2 * c].w,
                     ax[2 * c + 1].x, ax[2 * c + 1].y, ax[2 * c + 1].z, ax[2 * c + 1].w};
      short8v h8, l8;
#pragma unroll
      for (int j = 0; j < 8; ++j) {
        ushort h = f2bfu(vv[j]);
        float hf = __uint_as_float(((uint32_t)h) << 16);
        h8[j] = (short)h;
        l8[j] = (short)f2bfu(vv[j] - hf);
      }
      *(short8v*)&AhS[off] = h8;
      *(short8v*)&AlS[off] = l8;
      *(short8v*)&BhS[off] = bhv[c];
      *(short8v*)&BlS[off] = blv[c];
    }
    __syncthreads();
    if (ch < 7) LOADCHUNK((ch + 1) * 64);  // prefetch next chunk into regs

    // ---- MFMA phase: 3 split segments share the staged chunk ----
#pragma unroll
    for (int s = 0; s < 2; ++s) {
      const int kc = s * 4 + (L >> 4);
      short8v afh[4], afl[4], bfh[4], bfl[4];
#pragma unroll
      for (int m = 0; m < 4; ++m) {
        const int rl = wr + m * 16 + (L & 15);
        const int off = rl * 64 + ((kc * 8) ^ ((rl & 7) * 8));
        afh[m] = *(const short8v*)&AhS[off];
        afl[m] = *(const short8v*)&AlS[off];
      }
#pragma unroll
      for (int n = 0; n < 4; ++n) {
        const int cl = wc + n * 16 + (L & 15);
        const int off = cl * 64 + ((kc * 8) ^ ((cl & 7) * 8));
        bfh[n] = *(const short8v*)&BhS[off];
        bfl[n] = *(const short8v*)&BlS[off];
      }
#pragma unroll
      for (int m = 0; m < 4; ++m)
#pragma unroll
        for (int n = 0; n < 4; ++n) {
          acc[m][n] = __builtin_amdgcn_mfma_f32_16x16x32_bf16(afh[m], bfh[n], acc[m][n], 0, 0, 0);
          acc[m][n] = __builtin_amdgcn_mfma_f32_16x16x32_bf16(afh[m], bfl[n], acc[m][n], 0, 0, 0);
          acc[m][n] = __builtin_amdgcn_mfma_f32_16x16x32_bf16(afl[m], bfh[n], acc[m][n], 0, 0, 0);
        }
    }
    __syncthreads();
  }
#undef LOADCHUNK

  // ---- epilogue: q = csq - 2*dot_screen; per-row best-2 over this tile ----
  float cq[4];
#pragma unroll
  for (int n = 0; n < 4; ++n) cq[n] = csq[c0 + wc + n * 16 + (L & 15)];

#pragma unroll
  for (int m = 0; m < 4; ++m) {
#pragma unroll
    for (int i = 0; i < 4; ++i) {
      ull k1 = ~0ull, k2 = ~0ull;
#pragma unroll
      for (int n = 0; n < 4; ++n) {
        float q = cq[n] - 2.0f * acc[m][n][i];
        ull key = ((ull)fsort(q) << 32) | (uint32_t)(c0 + wc + n * 16 + (L & 15));
        if (key < k1) { k2 = k1; k1 = key; }
        else if (key < k2) k2 = key;
      }
#pragma unroll
      for (int mask = 1; mask <= 8; mask <<= 1) {
        ull o1 = __shfl_xor(k1, mask, 64);
        ull o2 = __shfl_xor(k2, mask, 64);
        if (o1 < k1) { ull n2 = umin64(k1, o2); k1 = o1; k2 = n2; }
        else { k2 = umin64(o1, k2); }
      }
      if ((L & 15) == 0) {
        int rl = wr + m * 16 + (L >> 4) * 4 + i;
        mb[rl][w & 1][0] = k1;
        mb[rl][w & 1][1] = k2;
      }
    }
  }
  __syncthreads();
  if (t < 128) {
    ull a1 = mb[t][0][0], a2 = mb[t][0][1];
    ull b1 = mb[t][1][0], b2 = mb[t][1][1];
    ull k1, k2;
    if (a1 < b1) { k1 = a1; k2 = umin64(a2, b1); }
    else { k1 = b1; k2 = umin64(b2, a1); }
    keys[(r0 + t) * 128 + cb * 2 + 0] = k1;
    keys[(r0 + t) * 128 + cb * 2 + 1] = k2;
  }
}

// ------- reduce: margin-filter, exact rescore (verified numerics), gather -------
__global__ __launch_bounds__(256)
void vq_reduce_kernel(const float* __restrict__ X, const float* __restrict__ CB,
                      const float* __restrict__ csq, const ull* __restrict__ keys,
                      float* __restrict__ out) {
  __shared__ int bidx[4];
  const int t = threadIdx.x;
  const int L = t & 63;
  const int w = t >> 6;
  const size_t row = (size_t)blockIdx.x * 4 + w;
  ulonglong2 kk = *(const ulonglong2*)(keys + row * 128 + L * 2);

  ull kmin = umin64(kk.x, kk.y);
#pragma unroll
  for (int m = 32; m; m >>= 1) {
    ull o = __shfl_xor(kmin, m, 64);
    if (o < kmin) kmin = o;
  }
  const float qcut = funsort((uint32_t)(kmin >> 32)) + MARGIN;

  ull bestE = ~0ull;
#pragma unroll
  for (int j = 0; j < 2; ++j) {
    ull key = j ? kk.y : kk.x;
    float q = funsort((uint32_t)(key >> 32));
    if (q <= qcut) {
      int idx = (int)(key & 0xffffffffu);
      const float* xp = X + row * DD;
      const float* cp = CB + (size_t)idx * DD;
      float xs;
      {
#pragma clang fp contract(off)
        float b0 = pairwise128_sq(xp), b1 = pairwise128_sq(xp + 128);
        float b2 = pairwise128_sq(xp + 256), b3 = pairwise128_sq(xp + 384);
        xs = (b0 + b1) + (b2 + b3);
      }
      float dot = 0.f;
      for (int c4 = 0; c4 < 128; ++c4) {  // sequential d ascending, FMA
        float4 a = *(const float4*)(xp + c4 * 4);
        float4 b = *(const float4*)(cp + c4 * 4);
        dot = __builtin_fmaf(a.x, b.x, dot);
        dot = __builtin_fmaf(a.y, b.y, dot);
        dot = __builtin_fmaf(a.z, b.z, dot);
        dot = __builtin_fmaf(a.w, b.w, dot);
      }
      float dist;
      {
#pragma clang fp contract(off)
        float m2 = 2.0f * dot;
        float t1 = xs - m2;
        dist = t1 + csq[idx];
      }
      ull ek = ((ull)fsort(dist) << 32) | (uint32_t)idx;
      if (ek < bestE) bestE = ek;
    }
  }
#pragma unroll
  for (int m = 32; m; m >>= 1) {
    ull o = __shfl_xor(bestE, m, 64);
    if (o < bestE) bestE = o;
  }
  if (L == 0) bidx[w] = (int)(bestE & 0xffffffffu);
  __syncthreads();

  const size_t r0 = (size_t)blockIdx.x * 4;
#pragma unroll
  for (int it = 0; it < 2; ++it) {
    int idx = t + it * 256;
    int rw = idx >> 7, c4 = idx & 127;
    float4 v = *(const float4*)(CB + (size_t)bidx[rw] * DD + c4 * 4);
    *(float4*)(out + (r0 + rw) * DD + c4 * 4) = v;
  }
}

// =================== fallback path (round-2, ws-free, replay-proven) ===================
constexpr int FBM = 128, FBN = 128, FBK = 32, FNT = 256;
constexpr int FKSPLIT = 4;
constexpr int FKPB = KK / FKSPLIT;

__global__ __launch_bounds__(FNT)
void vq_partial_kernel(const float* __restrict__ X, const float* __restrict__ CB,
                       float* __restrict__ keyout) {
  __shared__ float Xs[FBK][FBM + 4];
  __shared__ float Cs[FBK][FBN + 4];
  __shared__ float xblk[FBM][4];
  __shared__ float cblk[FBN][4];
  __shared__ float xsq[FBM];
  __shared__ float csq[FBN];

  const int t = threadIdx.x;
  const int tx = t & 15;
  const int ty = t >> 4;
  const int bid = blockIdx.x;
  const int xcd = bid & 7;
  const int loc = bid >> 3;
  const int ksplit = xcd >> 1;
  const int rowblk = (xcd & 1) * 64 + loc;
  const long r0 = (long)rowblk * FBM;
  const int kbase = ksplit * FKPB;

#pragma unroll
  for (int it = 0; it < 2; ++it) {
    int task = t + it * FNT;
    int row = task >> 2, blk = task & 3;
    xblk[row][blk] = pairwise128_sq(X + (r0 + row) * DD + blk * 128);
  }
  __syncthreads();
  if (t < FBM) {
#pragma clang fp contract(off)
    xsq[t] = (xblk[t][0] + xblk[t][1]) + (xblk[t][2] + xblk[t][3]);
  }

  uint64_t bestKey[8];
#pragma unroll
  for (int i = 0; i < 8; ++i) bestKey[i] = ~0ull;

  float4 xr[4], cr[4];
  for (int kt = 0; kt < FKPB / FBN; ++kt) {
    const int k0 = kbase + kt * FBN;
    __syncthreads();
#pragma unroll
    for (int it = 0; it < 4; ++it) {
      int idx = t + it * FNT;
      int row = idx >> 3, dg = (idx & 7) * 4;
      xr[it] = *(const float4*)(X + (r0 + row) * DD + dg);
      cr[it] = *(const float4*)(CB + (long)(k0 + row) * DD + dg);
    }
#pragma unroll
    for (int it = 0; it < 2; ++it) {
      int task = t + it * FNT;
      int cw = task >> 2, blk = task & 3;
      cblk[cw][blk] = pairwise128_sq(CB + (long)(k0 + cw) * DD + blk * 128);
    }
    __syncthreads();
    if (t < FBN) {
#pragma clang fp contract(off)
      csq[t] = (cblk[t][0] + cblk[t][1]) + (cblk[t][2] + cblk[t][3]);
    }

    float acc[8][8];
#pragma unroll
    for (int i = 0; i < 8; ++i)
#pragma unroll
      for (int j = 0; j < 8; ++j) acc[i][j] = 0.0f;

    for (int dc = 0; dc < DD; dc += FBK) {
#pragma unroll
      for (int it = 0; it < 4; ++it) {
        int idx = t + it * FNT;
        int row = idx >> 3, dg = (idx & 7) * 4;
        Xs[dg + 0][row] = xr[it].x; Xs[dg + 1][row] = xr[it].y;
        Xs[dg + 2][row] = xr[it].z; Xs[dg + 3][row] = xr[it].w;
        Cs[dg + 0][row] = cr[it].x; Cs[dg + 1][row] = cr[it].y;
        Cs[dg + 2][row] = cr[it].z; Cs[dg + 3][row] = cr[it].w;
      }
      if (dc + FBK < DD) {
#pragma unroll
        for (int it = 0; it < 4; ++it) {
          int idx = t + it * FNT;
          int row = idx >> 3, dg = (idx & 7) * 4 + dc + FBK;
          xr[it] = *(const float4*)(X + (r0 + row) * DD + dg);
          cr[it] = *(const float4*)(CB + (long)(k0 + row) * DD + dg);
        }
      }
      __syncthreads();
#pragma unroll 4
      for (int d = 0; d < FBK; ++d) {
        const float4 xa0 = *(const float4*)&Xs[d][ty * 4];
        const float4 xa1 = *(const float4*)&Xs[d][64 + ty * 4];
        const float4 cb0 = *(const float4*)&Cs[d][tx * 4];
        const float4 cb1 = *(const float4*)&Cs[d][64 + tx * 4];
        const float xv[8] = {xa0.x, xa0.y, xa0.z, xa0.w, xa1.x, xa1.y, xa1.z, xa1.w};
        const float cv[8] = {cb0.x, cb0.y, cb0.z, cb0.w, cb1.x, cb1.y, cb1.z, cb1.w};
#pragma unroll
        for (int i = 0; i < 8; ++i)
#pragma unroll
          for (int j = 0; j < 8; ++j)
            acc[i][j] = __builtin_fmaf(xv[i], cv[j], acc[i][j]);
      }
      __syncthreads();
    }
    {
#pragma clang fp contract(off)
#pragma unroll
      for (int i = 0; i < 8; ++i) {
        int rl = (i < 4) ? (ty * 4 + i) : (64 + ty * 4 + (i - 4));
        float xsv = xsq[rl];
#pragma unroll
        for (int j = 0; j < 8; ++j) {
          int cl = (j < 4) ? (tx * 4 + j) : (64 + tx * 4 + (j - 4));
          float m = 2.0f * acc[i][j];
          float t1 = xsv - m;
          float dist = t1 + csq[cl];
          uint64_t key = ((uint64_t)fsort(dist) << 32) | (uint32_t)(k0 + cl);
          if (key < bestKey[i]) bestKey[i] = key;
        }
      }
    }
  }
#pragma unroll
  for (int i = 0; i < 8; ++i) {
    ull k = bestKey[i];
#pragma unroll
    for (int m = 1; m <= 8; m <<= 1) {
      ull o = __shfl_xor(k, m, 64);
      if (o < k) k = o;
    }
    if (tx == 0) {
      int rl = (i < 4) ? (ty * 4 + i) : (64 + ty * 4 + (i - 4));
      *(ull*)(keyout + (r0 + rl) * DD + ksplit * 2) = k;
    }
  }
}

__global__ __launch_bounds__(FNT)
void vq_reduce_gather_kernel(const float* __restrict__ CB, float* __restrict__ out) {
  __shared__ int bidx[32];
  const int t = threadIdx.x;
  const long r0 = (long)blockIdx.x * 32;
  if (t < 32) {
    const ull* kp = (const ull*)(out + (r0 + t) * DD);
    ull k = kp[0];
#pragma unroll
    for (int s = 1; s < FKSPLIT; ++s) k = umin64(k, kp[s]);
    bidx[t] = (int)(k & 0xffffffffu);
  }
  __syncthreads();
#pragma unroll
  for (int it = 0; it < 16; ++it) {
    int idx = t + it * FNT;
    int row = idx >> 7, c4 = idx & 127;
    const float4 v = *(const float4*)(CB + (long)bidx[row] * DD + c4 * 4);
    *(float4*)(out + (r0 + row) * DD + c4 * 4) = v;
  }
}

extern "C" void kernel_launch(void* const* d_in, const int* in_sizes, int n_in,
                              void* d_out, int out_size, void* d_ws, size_t ws_size,
                              hipStream_t stream) {
  const float* X = (const float*)d_in[0];   // [16384, 512]
  const float* CB = (const float*)d_in[1];  // [8192, 512]
  float* out = (float*)d_out;

  if (ws_size >= WS_NEEDED) {
    ushort* Bh = (ushort*)d_ws;
    float* csqp = (float*)(Bh + BH_ELEMS);
    ull* keys = (ull*)(csqp + KK);
    hipLaunchKernelGGL(split_kernel, dim3(KK * 128 / 256), dim3(256), 0, stream, CB, Bh);
    hipLaunchKernelGGL(csq_kernel, dim3(KK / 64), dim3(256), 0, stream, CB, csqp);
    hipLaunchKernelGGL(vq_screen_kernel, dim3((NROWS / 128) * (KK / 128)), dim3(GNT), 0, stream,
                       X, Bh, csqp, keys);
    hipLaunchKernelGGL(vq_reduce_kernel, dim3(NROWS / 4), dim3(256), 0, stream,
                       X, CB, csqp, keys, out);
  } else {
    hipLaunchKernelGGL(vq_partial_kernel, dim3(512), dim3(FNT), 0, stream, X, CB, out);
    hipLaunchKernelGGL(vq_reduce_gather_kernel, dim3(NROWS / 32), dim3(FNT), 0, stream, CB, out);
  }
}

// Round 5
// 724.844 us; speedup vs baseline: 4.2080x; 1.1794x over previous
//
#include <hip/hip_runtime.h>
#include <cstdint>

constexpr int DD = 512;       // feature dim
constexpr int KK = 8192;      // codebook size
constexpr int NROWS = 16384;  // x rows
#define MARGIN 1.0f

// ws layout: Axp (fp16 X) | Bsp (fp16 hi|lo CB) | csq | keys
constexpr size_t AX_ELEMS = (size_t)NROWS * DD;    // ushort
constexpr size_t BH_ELEMS = (size_t)KK * 1024;     // ushort
constexpr size_t KEY_ELEMS = (size_t)NROWS * 128;  // ull
constexpr size_t WS_NEEDED =
    AX_ELEMS * 2 + BH_ELEMS * 2 + (size_t)KK * 4 + KEY_ELEMS * 8;  // 50,364,416 (== proven r3 bound)

typedef __attribute__((ext_vector_type(8))) short short8v;
typedef __attribute__((ext_vector_type(8))) _Float16 half8v;
typedef __attribute__((ext_vector_type(4))) float floatx4;
typedef unsigned long long ull;

__device__ __forceinline__ ull umin64(ull a, ull b) { return a < b ? a : b; }
__device__ __forceinline__ uint32_t fsort(float f) {
  uint32_t u = __float_as_uint(f);
  return (u & 0x80000000u) ? ~u : (u | 0x80000000u);
}
__device__ __forceinline__ float funsort(uint32_t u) {
  uint32_t f = (u & 0x80000000u) ? (u ^ 0x80000000u) : ~u;
  return __uint_as_float(f);
}

// numpy-style pairwise sum of squares over 128 contiguous floats
__device__ __forceinline__ float pairwise128_sq(const float* __restrict__ p) {
#pragma clang fp contract(off)
  float r[8];
  {
    float4 a = ((const float4*)p)[0];
    float4 b = ((const float4*)p)[1];
    r[0] = a.x * a.x; r[1] = a.y * a.y; r[2] = a.z * a.z; r[3] = a.w * a.w;
    r[4] = b.x * b.x; r[5] = b.y * b.y; r[6] = b.z * b.z; r[7] = b.w * b.w;
  }
  for (int i = 2; i < 32; i += 2) {
    float4 a = ((const float4*)p)[i];
    float4 b = ((const float4*)p)[i + 1];
    r[0] = r[0] + a.x * a.x; r[1] = r[1] + a.y * a.y;
    r[2] = r[2] + a.z * a.z; r[3] = r[3] + a.w * a.w;
    r[4] = r[4] + b.x * b.x; r[5] = r[5] + b.y * b.y;
    r[6] = r[6] + b.z * b.z; r[7] = r[7] + b.w * b.w;
  }
  return ((r[0] + r[1]) + (r[2] + r[3])) + ((r[4] + r[5]) + (r[6] + r[7]));
}

// ---------------- pre-pass: X fp32 -> fp16 (single) ----------------
__global__ __launch_bounds__(256)
void splitA_kernel(const float* __restrict__ src, ushort* __restrict__ dst) {
  int idx = blockIdx.x * 256 + threadIdx.x;  // one float4 per thread
  float4 v = *(const float4*)(src + (size_t)idx * 4);
  ushort h[4];
  float vv[4] = {v.x, v.y, v.z, v.w};
#pragma unroll
  for (int i = 0; i < 4; ++i) h[i] = __builtin_bit_cast(ushort, (_Float16)vv[i]);
  *(ushort4*)(dst + (size_t)idx * 4) = make_ushort4(h[0], h[1], h[2], h[3]);
}

// ---------------- pre-pass: CB fp32 -> fp16 hi|lo halves ----------------
__global__ __launch_bounds__(256)
void splitB_kernel(const float* __restrict__ src, ushort* __restrict__ dst) {
  int idx = blockIdx.x * 256 + threadIdx.x;  // one float4 per thread
  int row = idx >> 7, c4 = idx & 127;
  float4 v = *(const float4*)(src + (size_t)row * DD + c4 * 4);
  float vv[4] = {v.x, v.y, v.z, v.w};
  ushort h[4], l[4];
#pragma unroll
  for (int i = 0; i < 4; ++i) {
    _Float16 hf = (_Float16)vv[i];
    h[i] = __builtin_bit_cast(ushort, hf);
    l[i] = __builtin_bit_cast(ushort, (_Float16)(vv[i] - (float)hf));
  }
  ushort* d1 = dst + (size_t)row * 1024 + c4 * 4;
  *(ushort4*)d1 = make_ushort4(h[0], h[1], h[2], h[3]);
  *(ushort4*)(d1 + 512) = make_ushort4(l[0], l[1], l[2], l[3]);
}

// ---------------- pre-pass: c_sq (numpy pairwise) ----------------
__global__ __launch_bounds__(256)
void csq_kernel(const float* __restrict__ CB, float* __restrict__ csq) {
  __shared__ float cblk[64][4];
  int t = threadIdx.x;
  int r0 = blockIdx.x * 64;
  int row = t >> 2, blk = t & 3;
  cblk[row][blk] = pairwise128_sq(CB + (size_t)(r0 + row) * DD + blk * 128);
  __syncthreads();
  if (t < 64) {
#pragma clang fp contract(off)
    csq[r0 + t] = (cblk[t][0] + cblk[t][1]) + (cblk[t][2] + cblk[t][3]);
  }
}

// ------------- screening GEMM (fp16, 2 segments), keys -> d_ws -------------
__global__ __launch_bounds__(256, 3)
void vq_screen16_kernel(const ushort* __restrict__ Axp, const ushort* __restrict__ Bsp,
                        const float* __restrict__ csq, ull* __restrict__ keys) {
  __shared__ ushort AS[128 * 64];
  __shared__ ushort BhS[128 * 64];
  __shared__ ushort BlS[128 * 64];
  __shared__ ull mb[128][2][2];

  const int t = threadIdx.x;
  const int L = t & 63;
  const int w = t >> 6;
  const int wr = (w >> 1) * 64, wc = (w & 1) * 64;

  // XCD-aware swizzle, bijective for 8192 blocks
  const int bid = blockIdx.x;
  const int swz = (bid & 7) * 1024 + (bid >> 3);
  const int rb = swz & 127, cb = swz >> 7;
  const size_t r0 = (size_t)rb * 128, c0 = (size_t)cb * 128;

  // staging map: 4 tasks/thread; row = trow + 32c, k-granule kg (8 halfs)
  const int kg = t & 7;
  const int trow = t >> 3;  // 0..31
  const int swzoff = (kg * 8) ^ ((trow & 7) * 8);  // (trow+32c)&7 == trow&7

  floatx4 acc[4][4];
#pragma unroll
  for (int m = 0; m < 4; ++m)
#pragma unroll
    for (int n = 0; n < 4; ++n) acc[m][n] = (floatx4){0.f, 0.f, 0.f, 0.f};

  short8v rav[4], rbh[4], rbl[4];

#define LOADCHUNK(KC)                                                          \
  {                                                                            \
    _Pragma("unroll") for (int c = 0; c < 4; ++c) {                            \
      const int row = trow + 32 * c;                                           \
      rav[c] = *(const short8v*)(Axp + (r0 + row) * DD + (KC) * 64 + kg * 8);  \
      const ushort* pb = Bsp + (c0 + row) * 1024 + (KC) * 64 + kg * 8;         \
      rbh[c] = *(const short8v*)pb;                                            \
      rbl[c] = *(const short8v*)(pb + 512);                                    \
    }                                                                          \
  }

  LOADCHUNK(0);

  for (int kc = 0; kc < 8; ++kc) {
    // ---- write phase: regs -> swizzled LDS ----
#pragma unroll
    for (int c = 0; c < 4; ++c) {
      const int off = (trow + 32 * c) * 64 + swzoff;
      *(short8v*)&AS[off] = rav[c];
      *(short8v*)&BhS[off] = rbh[c];
      *(short8v*)&BlS[off] = rbl[c];
    }
    __syncthreads();
    if (kc < 7) LOADCHUNK(kc + 1);  // prefetch next chunk into regs

    // ---- MFMA phase: A(k) x Bhi(k), A(k) x Blo(k), accumulate both ----
#pragma unroll
    for (int s = 0; s < 2; ++s) {
      const int kcol = s * 4 + (L >> 4);
      half8v af[4], bfh[4], bfl[4];
#pragma unroll
      for (int m = 0; m < 4; ++m) {
        const int rl = wr + m * 16 + (L & 15);
        af[m] = *(const half8v*)&AS[rl * 64 + ((kcol * 8) ^ ((rl & 7) * 8))];
      }
#pragma unroll
      for (int n = 0; n < 4; ++n) {
        const int cl = wc + n * 16 + (L & 15);
        bfh[n] = *(const half8v*)&BhS[cl * 64 + ((kcol * 8) ^ ((cl & 7) * 8))];
      }
#pragma unroll
      for (int m = 0; m < 4; ++m)
#pragma unroll
        for (int n = 0; n < 4; ++n)
          acc[m][n] = __builtin_amdgcn_mfma_f32_16x16x32_f16(af[m], bfh[n], acc[m][n], 0, 0, 0);
#pragma unroll
      for (int n = 0; n < 4; ++n) {
        const int cl = wc + n * 16 + (L & 15);
        bfl[n] = *(const half8v*)&BlS[cl * 64 + ((kcol * 8) ^ ((cl & 7) * 8))];
      }
#pragma unroll
      for (int m = 0; m < 4; ++m)
#pragma unroll
        for (int n = 0; n < 4; ++n)
          acc[m][n] = __builtin_amdgcn_mfma_f32_16x16x32_f16(af[m], bfl[n], acc[m][n], 0, 0, 0);
    }
    __syncthreads();
  }
#undef LOADCHUNK

  // ---- epilogue: q = csq - 2*dot_screen; per-row best-2 over this tile ----
  float cq[4];
#pragma unroll
  for (int n = 0; n < 4; ++n) cq[n] = csq[c0 + wc + n * 16 + (L & 15)];

#pragma unroll
  for (int m = 0; m < 4; ++m) {
#pragma unroll
    for (int i = 0; i < 4; ++i) {
      ull k1 = ~0ull, k2 = ~0ull;
#pragma unroll
      for (int n = 0; n < 4; ++n) {
        float q = cq[n] - 2.0f * acc[m][n][i];
        ull key = ((ull)fsort(q) << 32) | (uint32_t)(c0 + wc + n * 16 + (L & 15));
        if (key < k1) { k2 = k1; k1 = key; }
        else if (key < k2) k2 = key;
      }
#pragma unroll
      for (int mask = 1; mask <= 8; mask <<= 1) {
        ull o1 = __shfl_xor(k1, mask, 64);
        ull o2 = __shfl_xor(k2, mask, 64);
        if (o1 < k1) { ull n2 = umin64(k1, o2); k1 = o1; k2 = n2; }
        else { k2 = umin64(o1, k2); }
      }
      if ((L & 15) == 0) {
        int rl = wr + m * 16 + (L >> 4) * 4 + i;
        mb[rl][w & 1][0] = k1;
        mb[rl][w & 1][1] = k2;
      }
    }
  }
  __syncthreads();
  if (t < 128) {
    ull a1 = mb[t][0][0], a2 = mb[t][0][1];
    ull b1 = mb[t][1][0], b2 = mb[t][1][1];
    ull k1, k2;
    if (a1 < b1) { k1 = a1; k2 = umin64(a2, b1); }
    else { k1 = b1; k2 = umin64(b2, a1); }
    keys[(r0 + t) * 128 + cb * 2 + 0] = k1;
    keys[(r0 + t) * 128 + cb * 2 + 1] = k2;
  }
}

// ------- reduce: margin-filter, exact rescore (verified numerics), gather -------
__global__ __launch_bounds__(256)
void vq_reduce_kernel(const float* __restrict__ X, const float* __restrict__ CB,
                      const float* __restrict__ csq, const ull* __restrict__ keys,
                      float* __restrict__ out) {
  __shared__ int bidx[4];
  const int t = threadIdx.x;
  const int L = t & 63;
  const int w = t >> 6;
  const size_t row = (size_t)blockIdx.x * 4 + w;
  ulonglong2 kk = *(const ulonglong2*)(keys + row * 128 + L * 2);

  ull kmin = umin64(kk.x, kk.y);
#pragma unroll
  for (int m = 32; m; m >>= 1) {
    ull o = __shfl_xor(kmin, m, 64);
    if (o < kmin) kmin = o;
  }
  const float qcut = funsort((uint32_t)(kmin >> 32)) + MARGIN;

  ull bestE = ~0ull;
#pragma unroll
  for (int j = 0; j < 2; ++j) {
    ull key = j ? kk.y : kk.x;
    float q = funsort((uint32_t)(key >> 32));
    if (q <= qcut) {
      int idx = (int)(key & 0xffffffffu);
      const float* xp = X + row * DD;
      const float* cp = CB + (size_t)idx * DD;
      float xs;
      {
#pragma clang fp contract(off)
        float b0 = pairwise128_sq(xp), b1 = pairwise128_sq(xp + 128);
        float b2 = pairwise128_sq(xp + 256), b3 = pairwise128_sq(xp + 384);
        xs = (b0 + b1) + (b2 + b3);
      }
      float dot = 0.f;
      for (int c4 = 0; c4 < 128; ++c4) {  // sequential d ascending, FMA
        float4 a = *(const float4*)(xp + c4 * 4);
        float4 b = *(const float4*)(cp + c4 * 4);
        dot = __builtin_fmaf(a.x, b.x, dot);
        dot = __builtin_fmaf(a.y, b.y, dot);
        dot = __builtin_fmaf(a.z, b.z, dot);
        dot = __builtin_fmaf(a.w, b.w, dot);
      }
      float dist;
      {
#pragma clang fp contract(off)
        float m2 = 2.0f * dot;
        float t1 = xs - m2;
        dist = t1 + csq[idx];
      }
      ull ek = ((ull)fsort(dist) << 32) | (uint32_t)idx;
      if (ek < bestE) bestE = ek;
    }
  }
#pragma unroll
  for (int m = 32; m; m >>= 1) {
    ull o = __shfl_xor(bestE, m, 64);
    if (o < bestE) bestE = o;
  }
  if (L == 0) bidx[w] = (int)(bestE & 0xffffffffu);
  __syncthreads();

  const size_t r0 = (size_t)blockIdx.x * 4;
#pragma unroll
  for (int it = 0; it < 2; ++it) {
    int idx = t + it * 256;
    int rw = idx >> 7, c4 = idx & 127;
    float4 v = *(const float4*)(CB + (size_t)bidx[rw] * DD + c4 * 4);
    *(float4*)(out + (r0 + rw) * DD + c4 * 4) = v;
  }
}

// =================== fallback path (round-2, ws-free, replay-proven) ===================
constexpr int FBM = 128, FBN = 128, FBK = 32, FNT = 256;
constexpr int FKSPLIT = 4;
constexpr int FKPB = KK / FKSPLIT;

__global__ __launch_bounds__(FNT)
void vq_partial_kernel(const float* __restrict__ X, const float* __restrict__ CB,
                       float* __restrict__ keyout) {
  __shared__ float Xs[FBK][FBM + 4];
  __shared__ float Cs[FBK][FBN + 4];
  __shared__ float xblk[FBM][4];
  __shared__ float cblk[FBN][4];
  __shared__ float xsq[FBM];
  __shared__ float csq[FBN];

  const int t = threadIdx.x;
  const int tx = t & 15;
  const int ty = t >> 4;
  const int bid = blockIdx.x;
  const int xcd = bid & 7;
  const int loc = bid >> 3;
  const int ksplit = xcd >> 1;
  const int rowblk = (xcd & 1) * 64 + loc;
  const long r0 = (long)rowblk * FBM;
  const int kbase = ksplit * FKPB;

#pragma unroll
  for (int it = 0; it < 2; ++it) {
    int task = t + it * FNT;
    int row = task >> 2, blk = task & 3;
    xblk[row][blk] = pairwise128_sq(X + (r0 + row) * DD + blk * 128);
  }
  __syncthreads();
  if (t < FBM) {
#pragma clang fp contract(off)
    xsq[t] = (xblk[t][0] + xblk[t][1]) + (xblk[t][2] + xblk[t][3]);
  }

  uint64_t bestKey[8];
#pragma unroll
  for (int i = 0; i < 8; ++i) bestKey[i] = ~0ull;

  float4 xr[4], cr[4];
  for (int kt = 0; kt < FKPB / FBN; ++kt) {
    const int k0 = kbase + kt * FBN;
    __syncthreads();
#pragma unroll
    for (int it = 0; it < 4; ++it) {
      int idx = t + it * FNT;
      int row = idx >> 3, dg = (idx & 7) * 4;
      xr[it] = *(const float4*)(X + (r0 + row) * DD + dg);
      cr[it] = *(const float4*)(CB + (long)(k0 + row) * DD + dg);
    }
#pragma unroll
    for (int it = 0; it < 2; ++it) {
      int task = t + it * FNT;
      int cw = task >> 2, blk = task & 3;
      cblk[cw][blk] = pairwise128_sq(CB + (long)(k0 + cw) * DD + blk * 128);
    }
    __syncthreads();
    if (t < FBN) {
#pragma clang fp contract(off)
      csq[t] = (cblk[t][0] + cblk[t][1]) + (cblk[t][2] + cblk[t][3]);
    }

    float acc[8][8];
#pragma unroll
    for (int i = 0; i < 8; ++i)
#pragma unroll
      for (int j = 0; j < 8; ++j) acc[i][j] = 0.0f;

    for (int dc = 0; dc < DD; dc += FBK) {
#pragma unroll
      for (int it = 0; it < 4; ++it) {
        int idx = t + it * FNT;
        int row = idx >> 3, dg = (idx & 7) * 4;
        Xs[dg + 0][row] = xr[it].x; Xs[dg + 1][row] = xr[it].y;
        Xs[dg + 2][row] = xr[it].z; Xs[dg + 3][row] = xr[it].w;
        Cs[dg + 0][row] = cr[it].x; Cs[dg + 1][row] = cr[it].y;
        Cs[dg + 2][row] = cr[it].z; Cs[dg + 3][row] = cr[it].w;
      }
      if (dc + FBK < DD) {
#pragma unroll
        for (int it = 0; it < 4; ++it) {
          int idx = t + it * FNT;
          int row = idx >> 3, dg = (idx & 7) * 4 + dc + FBK;
          xr[it] = *(const float4*)(X + (r0 + row) * DD + dg);
          cr[it] = *(const float4*)(CB + (long)(k0 + row) * DD + dg);
        }
      }
      __syncthreads();
#pragma unroll 4
      for (int d = 0; d < FBK; ++d) {
        const float4 xa0 = *(const float4*)&Xs[d][ty * 4];
        const float4 xa1 = *(const float4*)&Xs[d][64 + ty * 4];
        const float4 cb0 = *(const float4*)&Cs[d][tx * 4];
        const float4 cb1 = *(const float4*)&Cs[d][64 + tx * 4];
        const float xv[8] = {xa0.x, xa0.y, xa0.z, xa0.w, xa1.x, xa1.y, xa1.z, xa1.w};
        const float cv[8] = {cb0.x, cb0.y, cb0.z, cb0.w, cb1.x, cb1.y, cb1.z, cb1.w};
#pragma unroll
        for (int i = 0; i < 8; ++i)
#pragma unroll
          for (int j = 0; j < 8; ++j)
            acc[i][j] = __builtin_fmaf(xv[i], cv[j], acc[i][j]);
      }
      __syncthreads();
    }
    {
#pragma clang fp contract(off)
#pragma unroll
      for (int i = 0; i < 8; ++i) {
        int rl = (i < 4) ? (ty * 4 + i) : (64 + ty * 4 + (i - 4));
        float xsv = xsq[rl];
#pragma unroll
        for (int j = 0; j < 8; ++j) {
          int cl = (j < 4) ? (tx * 4 + j) : (64 + tx * 4 + (j - 4));
          float m = 2.0f * acc[i][j];
          float t1 = xsv - m;
          float dist = t1 + csq[cl];
          uint64_t key = ((uint64_t)fsort(dist) << 32) | (uint32_t)(k0 + cl);
          if (key < bestKey[i]) bestKey[i] = key;
        }
      }
    }
  }
#pragma unroll
  for (int i = 0; i < 8; ++i) {
    ull k = bestKey[i];
#pragma unroll
    for (int m = 1; m <= 8; m <<= 1) {
      ull o = __shfl_xor(k, m, 64);
      if (o < k) k = o;
    }
    if (tx == 0) {
      int rl = (i < 4) ? (ty * 4 + i) : (64 + ty * 4 + (i - 4));
      *(ull*)(keyout + (r0 + rl) * DD + ksplit * 2) = k;
    }
  }
}

__global__ __launch_bounds__(FNT)
void vq_reduce_gather_kernel(const float* __restrict__ CB, float* __restrict__ out) {
  __shared__ int bidx[32];
  const int t = threadIdx.x;
  const long r0 = (long)blockIdx.x * 32;
  if (t < 32) {
    const ull* kp = (const ull*)(out + (r0 + t) * DD);
    ull k = kp[0];
#pragma unroll
    for (int s = 1; s < FKSPLIT; ++s) k = umin64(k, kp[s]);
    bidx[t] = (int)(k & 0xffffffffu);
  }
  __syncthreads();
#pragma unroll
  for (int it = 0; it < 16; ++it) {
    int idx = t + it * FNT;
    int row = idx >> 7, c4 = idx & 127;
    const float4 v = *(const float4*)(CB + (long)bidx[row] * DD + c4 * 4);
    *(float4*)(out + (r0 + row) * DD + c4 * 4) = v;
  }
}

extern "C" void kernel_launch(void* const* d_in, const int* in_sizes, int n_in,
                              void* d_out, int out_size, void* d_ws, size_t ws_size,
                              hipStream_t stream) {
  const float* X = (const float*)d_in[0];   // [16384, 512]
  const float* CB = (const float*)d_in[1];  // [8192, 512]
  float* out = (float*)d_out;

  if (ws_size >= WS_NEEDED) {
    ushort* Axp = (ushort*)d_ws;
    ushort* Bsp = Axp + AX_ELEMS;
    float* csqp = (float*)(Bsp + BH_ELEMS);
    ull* keys = (ull*)(csqp + KK);
    hipLaunchKernelGGL(splitA_kernel, dim3(NROWS * DD / 4 / 256), dim3(256), 0, stream, X, Axp);
    hipLaunchKernelGGL(splitB_kernel, dim3(KK * 128 / 256), dim3(256), 0, stream, CB, Bsp);
    hipLaunchKernelGGL(csq_kernel, dim3(KK / 64), dim3(256), 0, stream, CB, csqp);
    hipLaunchKernelGGL(vq_screen16_kernel, dim3((NROWS / 128) * (KK / 128)), dim3(256), 0, stream,
                       Axp, Bsp, csqp, keys);
    hipLaunchKernelGGL(vq_reduce_kernel, dim3(NROWS / 4), dim3(256), 0, stream,
                       X, CB, csqp, keys, out);
  } else {
    hipLaunchKernelGGL(vq_partial_kernel, dim3(512), dim3(FNT), 0, stream, X, CB, out);
    hipLaunchKernelGGL(vq_reduce_gather_kernel, dim3(NROWS / 32), dim3(FNT), 0, stream, CB, out);
  }
}

// Round 6
// 384.197 us; speedup vs baseline: 7.9389x; 1.8866x over previous
//
#include <hip/hip_runtime.h>
#include <cstdint>

constexpr int DD = 512;       // feature dim
constexpr int KK = 8192;      // codebook size
constexpr int NROWS = 16384;  // x rows
#define MARGIN 1.0f

// ws layout: Axp (fp16 X) | Bsp (fp16 hi|lo CB) | csq | keys
constexpr size_t AX_ELEMS = (size_t)NROWS * DD;    // ushort
constexpr size_t BH_ELEMS = (size_t)KK * 1024;     // ushort
constexpr size_t KEY_ELEMS = (size_t)NROWS * 128;  // ull
constexpr size_t WS_NEEDED =
    AX_ELEMS * 2 + BH_ELEMS * 2 + (size_t)KK * 4 + KEY_ELEMS * 8;  // 50,364,416 (== proven r3 bound)

typedef __attribute__((ext_vector_type(8))) short short8v;
typedef __attribute__((ext_vector_type(8))) _Float16 half8v;
typedef __attribute__((ext_vector_type(4))) float floatx4;
typedef unsigned long long ull;

__device__ __forceinline__ ull umin64(ull a, ull b) { return a < b ? a : b; }
__device__ __forceinline__ uint32_t fsort(float f) {
  uint32_t u = __float_as_uint(f);
  return (u & 0x80000000u) ? ~u : (u | 0x80000000u);
}
__device__ __forceinline__ float funsort(uint32_t u) {
  uint32_t f = (u & 0x80000000u) ? (u ^ 0x80000000u) : ~u;
  return __uint_as_float(f);
}

// numpy-style pairwise sum of squares over 128 contiguous floats
__device__ __forceinline__ float pairwise128_sq(const float* __restrict__ p) {
#pragma clang fp contract(off)
  float r[8];
  {
    float4 a = ((const float4*)p)[0];
    float4 b = ((const float4*)p)[1];
    r[0] = a.x * a.x; r[1] = a.y * a.y; r[2] = a.z * a.z; r[3] = a.w * a.w;
    r[4] = b.x * b.x; r[5] = b.y * b.y; r[6] = b.z * b.z; r[7] = b.w * b.w;
  }
  for (int i = 2; i < 32; i += 2) {
    float4 a = ((const float4*)p)[i];
    float4 b = ((const float4*)p)[i + 1];
    r[0] = r[0] + a.x * a.x; r[1] = r[1] + a.y * a.y;
    r[2] = r[2] + a.z * a.z; r[3] = r[3] + a.w * a.w;
    r[4] = r[4] + b.x * b.x; r[5] = r[5] + b.y * b.y;
    r[6] = r[6] + b.z * b.z; r[7] = r[7] + b.w * b.w;
  }
  return ((r[0] + r[1]) + (r[2] + r[3])) + ((r[4] + r[5]) + (r[6] + r[7]));
}

// ---------------- pre-pass: X fp32 -> fp16 (single) ----------------
__global__ __launch_bounds__(256)
void splitA_kernel(const float* __restrict__ src, ushort* __restrict__ dst) {
  int idx = blockIdx.x * 256 + threadIdx.x;  // one float4 per thread
  float4 v = *(const float4*)(src + (size_t)idx * 4);
  ushort h[4];
  float vv[4] = {v.x, v.y, v.z, v.w};
#pragma unroll
  for (int i = 0; i < 4; ++i) h[i] = __builtin_bit_cast(ushort, (_Float16)vv[i]);
  *(ushort4*)(dst + (size_t)idx * 4) = make_ushort4(h[0], h[1], h[2], h[3]);
}

// ---------------- pre-pass: CB fp32 -> fp16 hi|lo halves ----------------
__global__ __launch_bounds__(256)
void splitB_kernel(const float* __restrict__ src, ushort* __restrict__ dst) {
  int idx = blockIdx.x * 256 + threadIdx.x;  // one float4 per thread
  int row = idx >> 7, c4 = idx & 127;
  float4 v = *(const float4*)(src + (size_t)row * DD + c4 * 4);
  float vv[4] = {v.x, v.y, v.z, v.w};
  ushort h[4], l[4];
#pragma unroll
  for (int i = 0; i < 4; ++i) {
    _Float16 hf = (_Float16)vv[i];
    h[i] = __builtin_bit_cast(ushort, hf);
    l[i] = __builtin_bit_cast(ushort, (_Float16)(vv[i] - (float)hf));
  }
  ushort* d1 = dst + (size_t)row * 1024 + c4 * 4;
  *(ushort4*)d1 = make_ushort4(h[0], h[1], h[2], h[3]);
  *(ushort4*)(d1 + 512) = make_ushort4(l[0], l[1], l[2], l[3]);
}

// ---------------- pre-pass: c_sq (numpy pairwise) ----------------
__global__ __launch_bounds__(256)
void csq_kernel(const float* __restrict__ CB, float* __restrict__ csq) {
  __shared__ float cblk[64][4];
  int t = threadIdx.x;
  int r0 = blockIdx.x * 64;
  int row = t >> 2, blk = t & 3;
  cblk[row][blk] = pairwise128_sq(CB + (size_t)(r0 + row) * DD + blk * 128);
  __syncthreads();
  if (t < 64) {
#pragma clang fp contract(off)
    csq[r0 + t] = (cblk[t][0] + cblk[t][1]) + (cblk[t][2] + cblk[t][3]);
  }
}

// ------------- screening GEMM (fp16, 2 segments), keys -> d_ws -------------
__global__ __launch_bounds__(256, 3)
void vq_screen16_kernel(const ushort* __restrict__ Axp, const ushort* __restrict__ Bsp,
                        const float* __restrict__ csq, ull* __restrict__ keys) {
  __shared__ ushort AS[128 * 64];
  __shared__ ushort BhS[128 * 64];
  __shared__ ushort BlS[128 * 64];
  __shared__ ull mb[128][2][2];

  const int t = threadIdx.x;
  const int L = t & 63;
  const int w = t >> 6;
  const int wr = (w >> 1) * 64, wc = (w & 1) * 64;

  // XCD-aware swizzle, bijective for 8192 blocks
  const int bid = blockIdx.x;
  const int swz = (bid & 7) * 1024 + (bid >> 3);
  const int rb = swz & 127, cb = swz >> 7;
  const size_t r0 = (size_t)rb * 128, c0 = (size_t)cb * 128;

  // staging map: 4 tasks/thread; row = trow + 32c, k-granule kg (8 halfs)
  const int kg = t & 7;
  const int trow = t >> 3;  // 0..31
  const int swzoff = (kg * 8) ^ ((trow & 7) * 8);  // (trow+32c)&7 == trow&7

  floatx4 acc[4][4];
#pragma unroll
  for (int m = 0; m < 4; ++m)
#pragma unroll
    for (int n = 0; n < 4; ++n) acc[m][n] = (floatx4){0.f, 0.f, 0.f, 0.f};

  short8v rav[4], rbh[4], rbl[4];

#define LOADCHUNK(KC)                                                          \
  {                                                                            \
    _Pragma("unroll") for (int c = 0; c < 4; ++c) {                            \
      const int row = trow + 32 * c;                                           \
      rav[c] = *(const short8v*)(Axp + (r0 + row) * DD + (KC) * 64 + kg * 8);  \
      const ushort* pb = Bsp + (c0 + row) * 1024 + (KC) * 64 + kg * 8;         \
      rbh[c] = *(const short8v*)pb;                                            \
      rbl[c] = *(const short8v*)(pb + 512);                                    \
    }                                                                          \
  }

  LOADCHUNK(0);

  for (int kc = 0; kc < 8; ++kc) {
    // ---- write phase: regs -> swizzled LDS ----
#pragma unroll
    for (int c = 0; c < 4; ++c) {
      const int off = (trow + 32 * c) * 64 + swzoff;
      *(short8v*)&AS[off] = rav[c];
      *(short8v*)&BhS[off] = rbh[c];
      *(short8v*)&BlS[off] = rbl[c];
    }
    __syncthreads();
    if (kc < 7) LOADCHUNK(kc + 1);  // prefetch next chunk into regs

    // ---- MFMA phase: A(k) x Bhi(k), A(k) x Blo(k), accumulate both ----
#pragma unroll
    for (int s = 0; s < 2; ++s) {
      const int kcol = s * 4 + (L >> 4);
      half8v af[4], bfh[4], bfl[4];
#pragma unroll
      for (int m = 0; m < 4; ++m) {
        const int rl = wr + m * 16 + (L & 15);
        af[m] = *(const half8v*)&AS[rl * 64 + ((kcol * 8) ^ ((rl & 7) * 8))];
      }
#pragma unroll
      for (int n = 0; n < 4; ++n) {
        const int cl = wc + n * 16 + (L & 15);
        bfh[n] = *(const half8v*)&BhS[cl * 64 + ((kcol * 8) ^ ((cl & 7) * 8))];
      }
#pragma unroll
      for (int m = 0; m < 4; ++m)
#pragma unroll
        for (int n = 0; n < 4; ++n)
          acc[m][n] = __builtin_amdgcn_mfma_f32_16x16x32_f16(af[m], bfh[n], acc[m][n], 0, 0, 0);
#pragma unroll
      for (int n = 0; n < 4; ++n) {
        const int cl = wc + n * 16 + (L & 15);
        bfl[n] = *(const half8v*)&BlS[cl * 64 + ((kcol * 8) ^ ((cl & 7) * 8))];
      }
#pragma unroll
      for (int m = 0; m < 4; ++m)
#pragma unroll
        for (int n = 0; n < 4; ++n)
          acc[m][n] = __builtin_amdgcn_mfma_f32_16x16x32_f16(af[m], bfl[n], acc[m][n], 0, 0, 0);
    }
    __syncthreads();
  }
#undef LOADCHUNK

  // ---- epilogue: q = csq - 2*dot_screen; per-row best-2 over this tile ----
  float cq[4];
#pragma unroll
  for (int n = 0; n < 4; ++n) cq[n] = csq[c0 + wc + n * 16 + (L & 15)];

#pragma unroll
  for (int m = 0; m < 4; ++m) {
#pragma unroll
    for (int i = 0; i < 4; ++i) {
      ull k1 = ~0ull, k2 = ~0ull;
#pragma unroll
      for (int n = 0; n < 4; ++n) {
        float q = cq[n] - 2.0f * acc[m][n][i];
        ull key = ((ull)fsort(q) << 32) | (uint32_t)(c0 + wc + n * 16 + (L & 15));
        if (key < k1) { k2 = k1; k1 = key; }
        else if (key < k2) k2 = key;
      }
#pragma unroll
      for (int mask = 1; mask <= 8; mask <<= 1) {
        ull o1 = __shfl_xor(k1, mask, 64);
        ull o2 = __shfl_xor(k2, mask, 64);
        if (o1 < k1) { ull n2 = umin64(k1, o2); k1 = o1; k2 = n2; }
        else { k2 = umin64(o1, k2); }
      }
      if ((L & 15) == 0) {
        int rl = wr + m * 16 + (L >> 4) * 4 + i;
        mb[rl][w & 1][0] = k1;
        mb[rl][w & 1][1] = k2;
      }
    }
  }
  __syncthreads();
  if (t < 128) {
    ull a1 = mb[t][0][0], a2 = mb[t][0][1];
    ull b1 = mb[t][1][0], b2 = mb[t][1][1];
    ull k1, k2;
    if (a1 < b1) { k1 = a1; k2 = umin64(a2, b1); }
    else { k1 = b1; k2 = umin64(b2, a1); }
    keys[(r0 + t) * 128 + cb * 2 + 0] = k1;
    keys[(r0 + t) * 128 + cb * 2 + 1] = k2;
  }
}

// ------- reduce v2: ballot margin-count, skip-if-unique, wave-parallel rescore -------
__global__ __launch_bounds__(256)
void vq_reduce_kernel(const float* __restrict__ X, const float* __restrict__ CB,
                      const float* __restrict__ csq, const ull* __restrict__ keys,
                      float* __restrict__ out) {
  __shared__ int bidx[4];
  const int t = threadIdx.x;
  const int L = t & 63;
  const int w = t >> 6;
  const size_t row = (size_t)blockIdx.x * 4 + w;
  ulonglong2 kk = *(const ulonglong2*)(keys + row * 128 + L * 2);

  ull kmin = umin64(kk.x, kk.y);
#pragma unroll
  for (int m = 32; m; m >>= 1) {
    ull o = __shfl_xor(kmin, m, 64);
    if (o < kmin) kmin = o;
  }
  const float qcut = funsort((uint32_t)(kmin >> 32)) + MARGIN;

  // candidates within margin (kmin always qualifies)
  const bool c0 = funsort((uint32_t)(kk.x >> 32)) <= qcut;
  const bool c1 = funsort((uint32_t)(kk.y >> 32)) <= qcut;
  const ull b0 = __ballot(c0);
  const ull b1 = __ballot(c1);
  const int total = __popcll(b0) + __popcll(b1);

  int winner;
  if (total <= 1) {
    // unique candidate: screen error (<~0.1) << MARGIN -> winner is exact argmin
    winner = (int)(kmin & 0xffffffffu);
  } else {
    // wave-parallel exact fp32 rescore of each candidate; x_sq drops out of
    // the per-row comparison (row-constant), so compare q = c_sq - 2*dot.
    const float* xp = X + row * DD;
    const float4 xa = ((const float4*)xp)[L * 2];
    const float4 xb = ((const float4*)xp)[L * 2 + 1];
    ull bestE = ~0ull;
#pragma unroll
    for (int pass = 0; pass < 2; ++pass) {
      ull mask = pass ? b1 : b0;
      while (mask) {
        const int lane = __ffsll(mask) - 1;
        mask &= mask - 1;
        const ull key = __shfl(pass ? kk.y : kk.x, lane, 64);
        const int idx = (int)(key & 0xffffffffu);
        const float* cp = CB + (size_t)idx * DD;
        const float4 ca = ((const float4*)cp)[L * 2];
        const float4 cb = ((const float4*)cp)[L * 2 + 1];
        float p = 0.f;
        p = __builtin_fmaf(xa.x, ca.x, p);
        p = __builtin_fmaf(xa.y, ca.y, p);
        p = __builtin_fmaf(xa.z, ca.z, p);
        p = __builtin_fmaf(xa.w, ca.w, p);
        p = __builtin_fmaf(xb.x, cb.x, p);
        p = __builtin_fmaf(xb.y, cb.y, p);
        p = __builtin_fmaf(xb.z, cb.z, p);
        p = __builtin_fmaf(xb.w, cb.w, p);
#pragma unroll
        for (int m = 32; m; m >>= 1) p += __shfl_xor(p, m, 64);
        const float q = csq[idx] - 2.0f * p;
        const ull ek = ((ull)fsort(q) << 32) | (uint32_t)idx;
        bestE = umin64(bestE, ek);
      }
    }
    winner = (int)(bestE & 0xffffffffu);
  }
  if (L == 0) bidx[w] = winner;
  __syncthreads();

  const size_t r0 = (size_t)blockIdx.x * 4;
#pragma unroll
  for (int it = 0; it < 2; ++it) {
    int idx = t + it * 256;
    int rw = idx >> 7, c4 = idx & 127;
    float4 v = *(const float4*)(CB + (size_t)bidx[rw] * DD + c4 * 4);
    *(float4*)(out + (r0 + rw) * DD + c4 * 4) = v;
  }
}

// =================== fallback path (round-2, ws-free, replay-proven) ===================
constexpr int FBM = 128, FBN = 128, FBK = 32, FNT = 256;
constexpr int FKSPLIT = 4;
constexpr int FKPB = KK / FKSPLIT;

__global__ __launch_bounds__(FNT)
void vq_partial_kernel(const float* __restrict__ X, const float* __restrict__ CB,
                       float* __restrict__ keyout) {
  __shared__ float Xs[FBK][FBM + 4];
  __shared__ float Cs[FBK][FBN + 4];
  __shared__ float xblk[FBM][4];
  __shared__ float cblk[FBN][4];
  __shared__ float xsq[FBM];
  __shared__ float csq[FBN];

  const int t = threadIdx.x;
  const int tx = t & 15;
  const int ty = t >> 4;
  const int bid = blockIdx.x;
  const int xcd = bid & 7;
  const int loc = bid >> 3;
  const int ksplit = xcd >> 1;
  const int rowblk = (xcd & 1) * 64 + loc;
  const long r0 = (long)rowblk * FBM;
  const int kbase = ksplit * FKPB;

#pragma unroll
  for (int it = 0; it < 2; ++it) {
    int task = t + it * FNT;
    int row = task >> 2, blk = task & 3;
    xblk[row][blk] = pairwise128_sq(X + (r0 + row) * DD + blk * 128);
  }
  __syncthreads();
  if (t < FBM) {
#pragma clang fp contract(off)
    xsq[t] = (xblk[t][0] + xblk[t][1]) + (xblk[t][2] + xblk[t][3]);
  }

  uint64_t bestKey[8];
#pragma unroll
  for (int i = 0; i < 8; ++i) bestKey[i] = ~0ull;

  float4 xr[4], cr[4];
  for (int kt = 0; kt < FKPB / FBN; ++kt) {
    const int k0 = kbase + kt * FBN;
    __syncthreads();
#pragma unroll
    for (int it = 0; it < 4; ++it) {
      int idx = t + it * FNT;
      int row = idx >> 3, dg = (idx & 7) * 4;
      xr[it] = *(const float4*)(X + (r0 + row) * DD + dg);
      cr[it] = *(const float4*)(CB + (long)(k0 + row) * DD + dg);
    }
#pragma unroll
    for (int it = 0; it < 2; ++it) {
      int task = t + it * FNT;
      int cw = task >> 2, blk = task & 3;
      cblk[cw][blk] = pairwise128_sq(CB + (long)(k0 + cw) * DD + blk * 128);
    }
    __syncthreads();
    if (t < FBN) {
#pragma clang fp contract(off)
      csq[t] = (cblk[t][0] + cblk[t][1]) + (cblk[t][2] + cblk[t][3]);
    }

    float acc[8][8];
#pragma unroll
    for (int i = 0; i < 8; ++i)
#pragma unroll
      for (int j = 0; j < 8; ++j) acc[i][j] = 0.0f;

    for (int dc = 0; dc < DD; dc += FBK) {
#pragma unroll
      for (int it = 0; it < 4; ++it) {
        int idx = t + it * FNT;
        int row = idx >> 3, dg = (idx & 7) * 4;
        Xs[dg + 0][row] = xr[it].x; Xs[dg + 1][row] = xr[it].y;
        Xs[dg + 2][row] = xr[it].z; Xs[dg + 3][row] = xr[it].w;
        Cs[dg + 0][row] = cr[it].x; Cs[dg + 1][row] = cr[it].y;
        Cs[dg + 2][row] = cr[it].z; Cs[dg + 3][row] = cr[it].w;
      }
      if (dc + FBK < DD) {
#pragma unroll
        for (int it = 0; it < 4; ++it) {
          int idx = t + it * FNT;
          int row = idx >> 3, dg = (idx & 7) * 4 + dc + FBK;
          xr[it] = *(const float4*)(X + (r0 + row) * DD + dg);
          cr[it] = *(const float4*)(CB + (long)(k0 + row) * DD + dg);
        }
      }
      __syncthreads();
#pragma unroll 4
      for (int d = 0; d < FBK; ++d) {
        const float4 xa0 = *(const float4*)&Xs[d][ty * 4];
        const float4 xa1 = *(const float4*)&Xs[d][64 + ty * 4];
        const float4 cb0 = *(const float4*)&Cs[d][tx * 4];
        const float4 cb1 = *(const float4*)&Cs[d][64 + tx * 4];
        const float xv[8] = {xa0.x, xa0.y, xa0.z, xa0.w, xa1.x, xa1.y, xa1.z, xa1.w};
        const float cv[8] = {cb0.x, cb0.y, cb0.z, cb0.w, cb1.x, cb1.y, cb1.z, cb1.w};
#pragma unroll
        for (int i = 0; i < 8; ++i)
#pragma unroll
          for (int j = 0; j < 8; ++j)
            acc[i][j] = __builtin_fmaf(xv[i], cv[j], acc[i][j]);
      }
      __syncthreads();
    }
    {
#pragma clang fp contract(off)
#pragma unroll
      for (int i = 0; i < 8; ++i) {
        int rl = (i < 4) ? (ty * 4 + i) : (64 + ty * 4 + (i - 4));
        float xsv = xsq[rl];
#pragma unroll
        for (int j = 0; j < 8; ++j) {
          int cl = (j < 4) ? (tx * 4 + j) : (64 + tx * 4 + (j - 4));
          float m = 2.0f * acc[i][j];
          float t1 = xsv - m;
          float dist = t1 + csq[cl];
          uint64_t key = ((uint64_t)fsort(dist) << 32) | (uint32_t)(k0 + cl);
          if (key < bestKey[i]) bestKey[i] = key;
        }
      }
    }
  }
#pragma unroll
  for (int i = 0; i < 8; ++i) {
    ull k = bestKey[i];
#pragma unroll
    for (int m = 1; m <= 8; m <<= 1) {
      ull o = __shfl_xor(k, m, 64);
      if (o < k) k = o;
    }
    if (tx == 0) {
      int rl = (i < 4) ? (ty * 4 + i) : (64 + ty * 4 + (i - 4));
      *(ull*)(keyout + (r0 + rl) * DD + ksplit * 2) = k;
    }
  }
}

__global__ __launch_bounds__(FNT)
void vq_reduce_gather_kernel(const float* __restrict__ CB, float* __restrict__ out) {
  __shared__ int bidx[32];
  const int t = threadIdx.x;
  const long r0 = (long)blockIdx.x * 32;
  if (t < 32) {
    const ull* kp = (const ull*)(out + (r0 + t) * DD);
    ull k = kp[0];
#pragma unroll
    for (int s = 1; s < FKSPLIT; ++s) k = umin64(k, kp[s]);
    bidx[t] = (int)(k & 0xffffffffu);
  }
  __syncthreads();
#pragma unroll
  for (int it = 0; it < 16; ++it) {
    int idx = t + it * FNT;
    int row = idx >> 7, c4 = idx & 127;
    const float4 v = *(const float4*)(CB + (long)bidx[row] * DD + c4 * 4);
    *(float4*)(out + (r0 + row) * DD + c4 * 4) = v;
  }
}

extern "C" void kernel_launch(void* const* d_in, const int* in_sizes, int n_in,
                              void* d_out, int out_size, void* d_ws, size_t ws_size,
                              hipStream_t stream) {
  const float* X = (const float*)d_in[0];   // [16384, 512]
  const float* CB = (const float*)d_in[1];  // [8192, 512]
  float* out = (float*)d_out;

  if (ws_size >= WS_NEEDED) {
    ushort* Axp = (ushort*)d_ws;
    ushort* Bsp = Axp + AX_ELEMS;
    float* csqp = (float*)(Bsp + BH_ELEMS);
    ull* keys = (ull*)(csqp + KK);
    hipLaunchKernelGGL(splitA_kernel, dim3(NROWS * DD / 4 / 256), dim3(256), 0, stream, X, Axp);
    hipLaunchKernelGGL(splitB_kernel, dim3(KK * 128 / 256), dim3(256), 0, stream, CB, Bsp);
    hipLaunchKernelGGL(csq_kernel, dim3(KK / 64), dim3(256), 0, stream, CB, csqp);
    hipLaunchKernelGGL(vq_screen16_kernel, dim3((NROWS / 128) * (KK / 128)), dim3(256), 0, stream,
                       Axp, Bsp, csqp, keys);
    hipLaunchKernelGGL(vq_reduce_kernel, dim3(NROWS / 4), dim3(256), 0, stream,
                       X, CB, csqp, keys, out);
  } else {
    hipLaunchKernelGGL(vq_partial_kernel, dim3(512), dim3(FNT), 0, stream, X, CB, out);
    hipLaunchKernelGGL(vq_reduce_gather_kernel, dim3(NROWS / 32), dim3(FNT), 0, stream, CB, out);
  }
}

// Round 7
// 265.900 us; speedup vs baseline: 11.4709x; 1.4449x over previous
//
#include <hip/hip_runtime.h>
#include <cstdint>

constexpr int DD = 512;       // feature dim
constexpr int KK = 8192;      // codebook size
constexpr int NROWS = 16384;  // x rows
#define MARGIN 1.0f

// ws layout: Axp (fp16 X) | Bfp (fp16 CB) | csq | keys
constexpr size_t AX_ELEMS = (size_t)NROWS * DD;    // ushort
constexpr size_t BF_ELEMS = (size_t)KK * DD;       // ushort
constexpr size_t KEY_ELEMS = (size_t)NROWS * 128;  // ull
constexpr size_t WS_NEEDED =
    AX_ELEMS * 2 + BF_ELEMS * 2 + (size_t)KK * 4 + KEY_ELEMS * 8;  // 41,975,808 (< proven 50.4MB)

typedef __attribute__((ext_vector_type(8))) short short8v;
typedef __attribute__((ext_vector_type(8))) _Float16 half8v;
typedef __attribute__((ext_vector_type(4))) float floatx4;
typedef unsigned long long ull;

__device__ __forceinline__ ull umin64(ull a, ull b) { return a < b ? a : b; }
__device__ __forceinline__ uint32_t fsort(float f) {
  uint32_t u = __float_as_uint(f);
  return (u & 0x80000000u) ? ~u : (u | 0x80000000u);
}
__device__ __forceinline__ float funsort(uint32_t u) {
  uint32_t f = (u & 0x80000000u) ? (u ^ 0x80000000u) : ~u;
  return __uint_as_float(f);
}

// async global->LDS, 16B per lane; LDS dest must be wave-uniform base
__device__ __forceinline__ void gl_lds16(const ushort* g, ushort* l) {
  __builtin_amdgcn_global_load_lds(
      (const __attribute__((address_space(1))) unsigned int*)g,
      (__attribute__((address_space(3))) unsigned int*)l, 16, 0, 0);
}

// numpy-style pairwise sum of squares over 128 contiguous floats
__device__ __forceinline__ float pairwise128_sq(const float* __restrict__ p) {
#pragma clang fp contract(off)
  float r[8];
  {
    float4 a = ((const float4*)p)[0];
    float4 b = ((const float4*)p)[1];
    r[0] = a.x * a.x; r[1] = a.y * a.y; r[2] = a.z * a.z; r[3] = a.w * a.w;
    r[4] = b.x * b.x; r[5] = b.y * b.y; r[6] = b.z * b.z; r[7] = b.w * b.w;
  }
  for (int i = 2; i < 32; i += 2) {
    float4 a = ((const float4*)p)[i];
    float4 b = ((const float4*)p)[i + 1];
    r[0] = r[0] + a.x * a.x; r[1] = r[1] + a.y * a.y;
    r[2] = r[2] + a.z * a.z; r[3] = r[3] + a.w * a.w;
    r[4] = r[4] + b.x * b.x; r[5] = r[5] + b.y * b.y;
    r[6] = r[6] + b.z * b.z; r[7] = r[7] + b.w * b.w;
  }
  return ((r[0] + r[1]) + (r[2] + r[3])) + ((r[4] + r[5]) + (r[6] + r[7]));
}

// ---------------- pre-pass: fp32 -> fp16 cast (flat) ----------------
__global__ __launch_bounds__(256)
void cast16_kernel(const float* __restrict__ src, ushort* __restrict__ dst) {
  int idx = blockIdx.x * 256 + threadIdx.x;  // one float4 per thread
  float4 v = *(const float4*)(src + (size_t)idx * 4);
  ushort h[4];
  float vv[4] = {v.x, v.y, v.z, v.w};
#pragma unroll
  for (int i = 0; i < 4; ++i) h[i] = __builtin_bit_cast(ushort, (_Float16)vv[i]);
  *(ushort4*)(dst + (size_t)idx * 4) = make_ushort4(h[0], h[1], h[2], h[3]);
}

// ---------------- pre-pass: c_sq (numpy pairwise) ----------------
__global__ __launch_bounds__(256)
void csq_kernel(const float* __restrict__ CB, float* __restrict__ csq) {
  __shared__ float cblk[64][4];
  int t = threadIdx.x;
  int r0 = blockIdx.x * 64;
  int row = t >> 2, blk = t & 3;
  cblk[row][blk] = pairwise128_sq(CB + (size_t)(r0 + row) * DD + blk * 128);
  __syncthreads();
  if (t < 64) {
#pragma clang fp contract(off)
    csq[r0 + t] = (cblk[t][0] + cblk[t][1]) + (cblk[t][2] + cblk[t][3]);
  }
}

// ------------- screening GEMM (fp16 single, K=512), gload_lds staging -------------
__global__ __launch_bounds__(256, 4)
void vq_screen16_kernel(const ushort* __restrict__ Axp, const ushort* __restrict__ Bfp,
                        const float* __restrict__ csq, ull* __restrict__ keys) {
  __shared__ ushort AS[128 * 64];
  __shared__ ushort BS[128 * 64];
  __shared__ ull mb[128][2][2];

  const int t = threadIdx.x;
  const int L = t & 63;
  const int w = t >> 6;
  const int wr = (w >> 1) * 64, wc = (w & 1) * 64;

  // XCD-aware swizzle, bijective for 8192 blocks
  const int bid = blockIdx.x;
  const int swz = (bid & 7) * 1024 + (bid >> 3);
  const int rb = swz & 127, cb = swz >> 7;
  const size_t r0 = (size_t)rb * 128, c0 = (size_t)cb * 128;

  // gload_lds: wave issue j covers rows w*32+j*8 .. +7 (1KB linear LDS).
  // lane l lands at row l>>3, dest-granule l&7; source supplies the
  // inverse-swizzled granule (l&7)^(l>>3) so swizzled READS stay valid.
  const int lrow = L >> 3;
  const int lgr = (L & 7) ^ lrow;
  const ushort* srcA0 = Axp + (r0 + w * 32 + lrow) * DD + lgr * 8;
  const ushort* srcB0 = Bfp + (c0 + w * 32 + lrow) * DD + lgr * 8;

  floatx4 acc[4][4];
#pragma unroll
  for (int m = 0; m < 4; ++m)
#pragma unroll
    for (int n = 0; n < 4; ++n) acc[m][n] = (floatx4){0.f, 0.f, 0.f, 0.f};

  for (int kc = 0; kc < 8; ++kc) {
    if (kc) __syncthreads();  // all readers done before clobbering the buffer
#pragma unroll
    for (int j = 0; j < 4; ++j) {
      gl_lds16(srcA0 + (size_t)j * 8 * DD + kc * 64, &AS[(w * 32 + j * 8) * 64]);
      gl_lds16(srcB0 + (size_t)j * 8 * DD + kc * 64, &BS[(w * 32 + j * 8) * 64]);
    }
    __syncthreads();  // vmcnt(0)+lgkmcnt(0) drain: staged data visible

#pragma unroll
    for (int s = 0; s < 2; ++s) {
      const int kcol = s * 4 + (L >> 4);
      half8v af[4], bf[4];
#pragma unroll
      for (int m = 0; m < 4; ++m) {
        const int rl = wr + m * 16 + (L & 15);
        af[m] = *(const half8v*)&AS[rl * 64 + ((kcol * 8) ^ ((rl & 7) * 8))];
      }
#pragma unroll
      for (int n = 0; n < 4; ++n) {
        const int cl = wc + n * 16 + (L & 15);
        bf[n] = *(const half8v*)&BS[cl * 64 + ((kcol * 8) ^ ((cl & 7) * 8))];
      }
#pragma unroll
      for (int m = 0; m < 4; ++m)
#pragma unroll
        for (int n = 0; n < 4; ++n)
          acc[m][n] = __builtin_amdgcn_mfma_f32_16x16x32_f16(af[m], bf[n], acc[m][n], 0, 0, 0);
    }
  }

  // ---- epilogue: q = csq - 2*dot_screen; per-row best-2 over this tile ----
  float cq[4];
#pragma unroll
  for (int n = 0; n < 4; ++n) cq[n] = csq[c0 + wc + n * 16 + (L & 15)];

#pragma unroll
  for (int m = 0; m < 4; ++m) {
#pragma unroll
    for (int i = 0; i < 4; ++i) {
      ull k1 = ~0ull, k2 = ~0ull;
#pragma unroll
      for (int n = 0; n < 4; ++n) {
        float q = cq[n] - 2.0f * acc[m][n][i];
        ull key = ((ull)fsort(q) << 32) | (uint32_t)(c0 + wc + n * 16 + (L & 15));
        if (key < k1) { k2 = k1; k1 = key; }
        else if (key < k2) k2 = key;
      }
#pragma unroll
      for (int mask = 1; mask <= 8; mask <<= 1) {
        ull o1 = __shfl_xor(k1, mask, 64);
        ull o2 = __shfl_xor(k2, mask, 64);
        if (o1 < k1) { ull n2 = umin64(k1, o2); k1 = o1; k2 = n2; }
        else { k2 = umin64(o1, k2); }
      }
      if ((L & 15) == 0) {
        int rl = wr + m * 16 + (L >> 4) * 4 + i;
        mb[rl][w & 1][0] = k1;
        mb[rl][w & 1][1] = k2;
      }
    }
  }
  __syncthreads();
  if (t < 128) {
    ull a1 = mb[t][0][0], a2 = mb[t][0][1];
    ull b1 = mb[t][1][0], b2 = mb[t][1][1];
    ull k1, k2;
    if (a1 < b1) { k1 = a1; k2 = umin64(a2, b1); }
    else { k1 = b1; k2 = umin64(b2, a1); }
    keys[(r0 + t) * 128 + cb * 2 + 0] = k1;
    keys[(r0 + t) * 128 + cb * 2 + 1] = k2;
  }
}

// ------- reduce: ballot margin-count, skip-if-unique, wave-parallel rescore -------
__global__ __launch_bounds__(256)
void vq_reduce_kernel(const float* __restrict__ X, const float* __restrict__ CB,
                      const float* __restrict__ csq, const ull* __restrict__ keys,
                      float* __restrict__ out) {
  __shared__ int bidx[4];
  const int t = threadIdx.x;
  const int L = t & 63;
  const int w = t >> 6;
  const size_t row = (size_t)blockIdx.x * 4 + w;
  ulonglong2 kk = *(const ulonglong2*)(keys + row * 128 + L * 2);

  ull kmin = umin64(kk.x, kk.y);
#pragma unroll
  for (int m = 32; m; m >>= 1) {
    ull o = __shfl_xor(kmin, m, 64);
    if (o < kmin) kmin = o;
  }
  const float qcut = funsort((uint32_t)(kmin >> 32)) + MARGIN;

  // candidates within margin (kmin always qualifies)
  const bool q0 = funsort((uint32_t)(kk.x >> 32)) <= qcut;
  const bool q1 = funsort((uint32_t)(kk.y >> 32)) <= qcut;
  const ull b0 = __ballot(q0);
  const ull b1 = __ballot(q1);
  const int total = __popcll(b0) + __popcll(b1);

  int winner;
  if (total <= 1) {
    // unique candidate: screen error (<~0.1) << MARGIN -> winner is exact argmin
    winner = (int)(kmin & 0xffffffffu);
  } else {
    // wave-parallel exact fp32 rescore; x_sq is row-constant and drops out,
    // so compare q = c_sq - 2*dot.
    const float* xp = X + row * DD;
    const float4 xa = ((const float4*)xp)[L * 2];
    const float4 xb = ((const float4*)xp)[L * 2 + 1];
    ull bestE = ~0ull;
#pragma unroll
    for (int pass = 0; pass < 2; ++pass) {
      ull mask = pass ? b1 : b0;
      while (mask) {
        const int lane = __ffsll(mask) - 1;
        mask &= mask - 1;
        const ull key = __shfl(pass ? kk.y : kk.x, lane, 64);
        const int idx = (int)(key & 0xffffffffu);
        const float* cp = CB + (size_t)idx * DD;
        const float4 ca = ((const float4*)cp)[L * 2];
        const float4 cbv = ((const float4*)cp)[L * 2 + 1];
        float p = 0.f;
        p = __builtin_fmaf(xa.x, ca.x, p);
        p = __builtin_fmaf(xa.y, ca.y, p);
        p = __builtin_fmaf(xa.z, ca.z, p);
        p = __builtin_fmaf(xa.w, ca.w, p);
        p = __builtin_fmaf(xb.x, cbv.x, p);
        p = __builtin_fmaf(xb.y, cbv.y, p);
        p = __builtin_fmaf(xb.z, cbv.z, p);
        p = __builtin_fmaf(xb.w, cbv.w, p);
#pragma unroll
        for (int m = 32; m; m >>= 1) p += __shfl_xor(p, m, 64);
        const float q = csq[idx] - 2.0f * p;
        const ull ek = ((ull)fsort(q) << 32) | (uint32_t)idx;
        bestE = umin64(bestE, ek);
      }
    }
    winner = (int)(bestE & 0xffffffffu);
  }
  if (L == 0) bidx[w] = winner;
  __syncthreads();

  const size_t r0 = (size_t)blockIdx.x * 4;
#pragma unroll
  for (int it = 0; it < 2; ++it) {
    int idx = t + it * 256;
    int rw = idx >> 7, c4 = idx & 127;
    float4 v = *(const float4*)(CB + (size_t)bidx[rw] * DD + c4 * 4);
    *(float4*)(out + (r0 + rw) * DD + c4 * 4) = v;
  }
}

// =================== fallback path (round-2, ws-free, replay-proven) ===================
constexpr int FBM = 128, FBN = 128, FBK = 32, FNT = 256;
constexpr int FKSPLIT = 4;
constexpr int FKPB = KK / FKSPLIT;

__global__ __launch_bounds__(FNT)
void vq_partial_kernel(const float* __restrict__ X, const float* __restrict__ CB,
                       float* __restrict__ keyout) {
  __shared__ float Xs[FBK][FBM + 4];
  __shared__ float Cs[FBK][FBN + 4];
  __shared__ float xblk[FBM][4];
  __shared__ float cblk[FBN][4];
  __shared__ float xsq[FBM];
  __shared__ float csq[FBN];

  const int t = threadIdx.x;
  const int tx = t & 15;
  const int ty = t >> 4;
  const int bid = blockIdx.x;
  const int xcd = bid & 7;
  const int loc = bid >> 3;
  const int ksplit = xcd >> 1;
  const int rowblk = (xcd & 1) * 64 + loc;
  const long r0 = (long)rowblk * FBM;
  const int kbase = ksplit * FKPB;

#pragma unroll
  for (int it = 0; it < 2; ++it) {
    int task = t + it * FNT;
    int row = task >> 2, blk = task & 3;
    xblk[row][blk] = pairwise128_sq(X + (r0 + row) * DD + blk * 128);
  }
  __syncthreads();
  if (t < FBM) {
#pragma clang fp contract(off)
    xsq[t] = (xblk[t][0] + xblk[t][1]) + (xblk[t][2] + xblk[t][3]);
  }

  uint64_t bestKey[8];
#pragma unroll
  for (int i = 0; i < 8; ++i) bestKey[i] = ~0ull;

  float4 xr[4], cr[4];
  for (int kt = 0; kt < FKPB / FBN; ++kt) {
    const int k0 = kbase + kt * FBN;
    __syncthreads();
#pragma unroll
    for (int it = 0; it < 4; ++it) {
      int idx = t + it * FNT;
      int row = idx >> 3, dg = (idx & 7) * 4;
      xr[it] = *(const float4*)(X + (r0 + row) * DD + dg);
      cr[it] = *(const float4*)(CB + (long)(k0 + row) * DD + dg);
    }
#pragma unroll
    for (int it = 0; it < 2; ++it) {
      int task = t + it * FNT;
      int cw = task >> 2, blk = task & 3;
      cblk[cw][blk] = pairwise128_sq(CB + (long)(k0 + cw) * DD + blk * 128);
    }
    __syncthreads();
    if (t < FBN) {
#pragma clang fp contract(off)
      csq[t] = (cblk[t][0] + cblk[t][1]) + (cblk[t][2] + cblk[t][3]);
    }

    float acc[8][8];
#pragma unroll
    for (int i = 0; i < 8; ++i)
#pragma unroll
      for (int j = 0; j < 8; ++j) acc[i][j] = 0.0f;

    for (int dc = 0; dc < DD; dc += FBK) {
#pragma unroll
      for (int it = 0; it < 4; ++it) {
        int idx = t + it * FNT;
        int row = idx >> 3, dg = (idx & 7) * 4;
        Xs[dg + 0][row] = xr[it].x; Xs[dg + 1][row] = xr[it].y;
        Xs[dg + 2][row] = xr[it].z; Xs[dg + 3][row] = xr[it].w;
        Cs[dg + 0][row] = cr[it].x; Cs[dg + 1][row] = cr[it].y;
        Cs[dg + 2][row] = cr[it].z; Cs[dg + 3][row] = cr[it].w;
      }
      if (dc + FBK < DD) {
#pragma unroll
        for (int it = 0; it < 4; ++it) {
          int idx = t + it * FNT;
          int row = idx >> 3, dg = (idx & 7) * 4 + dc + FBK;
          xr[it] = *(const float4*)(X + (r0 + row) * DD + dg);
          cr[it] = *(const float4*)(CB + (long)(k0 + row) * DD + dg);
        }
      }
      __syncthreads();
#pragma unroll 4
      for (int d = 0; d < FBK; ++d) {
        const float4 xa0 = *(const float4*)&Xs[d][ty * 4];
        const float4 xa1 = *(const float4*)&Xs[d][64 + ty * 4];
        const float4 cb0 = *(const float4*)&Cs[d][tx * 4];
        const float4 cb1 = *(const float4*)&Cs[d][64 + tx * 4];
        const float xv[8] = {xa0.x, xa0.y, xa0.z, xa0.w, xa1.x, xa1.y, xa1.z, xa1.w};
        const float cv[8] = {cb0.x, cb0.y, cb0.z, cb0.w, cb1.x, cb1.y, cb1.z, cb1.w};
#pragma unroll
        for (int i = 0; i < 8; ++i)
#pragma unroll
          for (int j = 0; j < 8; ++j)
            acc[i][j] = __builtin_fmaf(xv[i], cv[j], acc[i][j]);
      }
      __syncthreads();
    }
    {
#pragma clang fp contract(off)
#pragma unroll
      for (int i = 0; i < 8; ++i) {
        int rl = (i < 4) ? (ty * 4 + i) : (64 + ty * 4 + (i - 4));
        float xsv = xsq[rl];
#pragma unroll
        for (int j = 0; j < 8; ++j) {
          int cl = (j < 4) ? (tx * 4 + j) : (64 + tx * 4 + (j - 4));
          float m = 2.0f * acc[i][j];
          float t1 = xsv - m;
          float dist = t1 + csq[cl];
          uint64_t key = ((uint64_t)fsort(dist) << 32) | (uint32_t)(k0 + cl);
          if (key < bestKey[i]) bestKey[i] = key;
        }
      }
    }
  }
#pragma unroll
  for (int i = 0; i < 8; ++i) {
    ull k = bestKey[i];
#pragma unroll
    for (int m = 1; m <= 8; m <<= 1) {
      ull o = __shfl_xor(k, m, 64);
      if (o < k) k = o;
    }
    if (tx == 0) {
      int rl = (i < 4) ? (ty * 4 + i) : (64 + ty * 4 + (i - 4));
      *(ull*)(keyout + (r0 + rl) * DD + ksplit * 2) = k;
    }
  }
}

__global__ __launch_bounds__(FNT)
void vq_reduce_gather_kernel(const float* __restrict__ CB, float* __restrict__ out) {
  __shared__ int bidx[32];
  const int t = threadIdx.x;
  const long r0 = (long)blockIdx.x * 32;
  if (t < 32) {
    const ull* kp = (const ull*)(out + (r0 + t) * DD);
    ull k = kp[0];
#pragma unroll
    for (int s = 1; s < FKSPLIT; ++s) k = umin64(k, kp[s]);
    bidx[t] = (int)(k & 0xffffffffu);
  }
  __syncthreads();
#pragma unroll
  for (int it = 0; it < 16; ++it) {
    int idx = t + it * FNT;
    int row = idx >> 7, c4 = idx & 127;
    const float4 v = *(const float4*)(CB + (long)bidx[row] * DD + c4 * 4);
    *(float4*)(out + (r0 + row) * DD + c4 * 4) = v;
  }
}

extern "C" void kernel_launch(void* const* d_in, const int* in_sizes, int n_in,
                              void* d_out, int out_size, void* d_ws, size_t ws_size,
                              hipStream_t stream) {
  const float* X = (const float*)d_in[0];   // [16384, 512]
  const float* CB = (const float*)d_in[1];  // [8192, 512]
  float* out = (float*)d_out;

  if (ws_size >= WS_NEEDED) {
    ushort* Axp = (ushort*)d_ws;
    ushort* Bfp = Axp + AX_ELEMS;
    float* csqp = (float*)(Bfp + BF_ELEMS);
    ull* keys = (ull*)(csqp + KK);
    hipLaunchKernelGGL(cast16_kernel, dim3(NROWS * DD / 4 / 256), dim3(256), 0, stream, X, Axp);
    hipLaunchKernelGGL(cast16_kernel, dim3(KK * DD / 4 / 256), dim3(256), 0, stream, CB, Bfp);
    hipLaunchKernelGGL(csq_kernel, dim3(KK / 64), dim3(256), 0, stream, CB, csqp);
    hipLaunchKernelGGL(vq_screen16_kernel, dim3((NROWS / 128) * (KK / 128)), dim3(256), 0, stream,
                       Axp, Bfp, csqp, keys);
    hipLaunchKernelGGL(vq_reduce_kernel, dim3(NROWS / 4), dim3(256), 0, stream,
                       X, CB, csqp, keys, out);
  } else {
    hipLaunchKernelGGL(vq_partial_kernel, dim3(512), dim3(FNT), 0, stream, X, CB, out);
    hipLaunchKernelGGL(vq_reduce_gather_kernel, dim3(NROWS / 32), dim3(FNT), 0, stream, CB, out);
  }
}